// Round 4
// baseline (3151.283 us; speedup 1.0000x reference)
//
#include <hip/hip_runtime.h>
#include <cstdint>

typedef __attribute__((ext_vector_type(4))) float f32x4;
typedef __attribute__((ext_vector_type(8))) short s16x8;
typedef unsigned short u16;
typedef unsigned int u32;
typedef __attribute__((address_space(1))) void gas_void;
typedef __attribute__((address_space(3))) void las_void;

#define B_ 4
#define T_ 1024
#define V_ 32000
#define D_ 1024
#define H_ 16
#define HS_ 64
#define FF_ 4096
#define L_ 8
#define BT_ (B_ * T_)

__device__ __forceinline__ float bf2f(u16 h) { return __uint_as_float(((u32)h) << 16); }
__device__ __forceinline__ u16 f2bf(float f) {
  u32 u = __float_as_uint(f);
  u += 0x7fffu + ((u >> 16) & 1u);
  return (u16)(u >> 16);
}

// async global->LDS, 16B per lane; lds dest must be wave-uniform base (+lane*16 by HW)
__device__ __forceinline__ void gld16(const void* g, void* l) {
  __builtin_amdgcn_global_load_lds((gas_void*)(uintptr_t)g,
                                   (las_void*)(u32)(uintptr_t)l, 16, 0, 0);
}

// ---------------------------------------------------------------------------
// gemm256: C[M,N] = A[M,K] @ Bt^T.  256x256 tile, BK=64, 8 waves (2Mx4N),
// 8-phase schedule w/ counted vmcnt (T3+T4), setprio (T5), XCD swizzle (T1).
// Requires M%256==0, N%256==0, K%128==0, K>=256, grid%8==0.
// Main loop runs NI-1 iterations (all stages valid -> vmcnt counts exact);
// peeled epilogue iteration drains with vmcnt 8 -> 4 -> 0.
// EPI: 0 = bf16 out; 2 = bf16 + bias + relu; 3 = f32 + bias.
// ---------------------------------------------------------------------------
template <int EPI>
__global__ __launch_bounds__(512, 2) void gemm256(
    const u16* __restrict__ A, const u16* __restrict__ Bt,
    const float* __restrict__ bias, float* Cf, u16* Cb,
    int M, int N, int K, int nrowb) {
  __shared__ u16 lds[2][2][2][8192];  // [buf][khalf][A/B][256*32] = 128 KiB
  const int tid = threadIdx.x;
  const int lane = tid & 63;
  const int lr = lane & 15, hi = lane >> 4;
  const int wid = tid >> 6;
  const int wm128 = (wid >> 2) << 7;
  const int wn64 = (wid & 3) << 6;
  const int logical = ((int)blockIdx.x & 7) * ((int)gridDim.x >> 3) + ((int)blockIdx.x >> 3);
  const int row0 = (logical % nrowb) << 8;
  const int col0 = (logical / nrowb) << 8;
  const int NT = K >> 6;
  const int srow = tid >> 2;   // staging row within 8KB shot
  const int schunk = tid & 3;  // staging 16B chunk
  const int xo = (hi ^ (lr & 3)) << 4;  // frag-read swizzle byte offset

  f32x4 acc[32];
#pragma unroll
  for (int i = 0; i < 32; ++i) acc[i] = f32x4{0.f, 0.f, 0.f, 0.f};

#define VMW(N) asm volatile("s_waitcnt vmcnt(" #N ")" ::: "memory")

#define STG(DB, DK, OP, KT)                                                    \
  {                                                                            \
    const u16* sp_ = (OP) ? Bt : A;                                            \
    const int base_ = (OP) ? col0 : row0;                                      \
    const int c0_ = ((KT) << 6) + ((DK) << 5);                                 \
    _Pragma("unroll")                                                          \
    for (int sh_ = 0; sh_ < 2; ++sh_) {                                        \
      const int rr_ = (sh_ << 7) + srow;                                       \
      gld16(sp_ + (size_t)(base_ + rr_) * K + c0_ + ((schunk ^ (rr_ & 3)) << 3), \
            (char*)&lds[DB][DK][OP][0] + (sh_ << 13) + (wid << 10));           \
    }                                                                          \
  }

#define PHASE(BUF, MH, KS, STG_STMT, VM_STMT)                                  \
  {                                                                            \
    __builtin_amdgcn_sched_barrier(0);                                         \
    const char* As_ = (const char*)&lds[BUF][KS][0][0];                        \
    const char* Bs_ = (const char*)&lds[BUF][KS][1][0];                        \
    const int ra_ = wm128 + ((MH) << 6) + lr;                                  \
    const int rb_ = wn64 + lr;                                                 \
    s16x8 af_[4], bf_[4];                                                      \
    _Pragma("unroll")                                                          \
    for (int q_ = 0; q_ < 4; ++q_) {                                           \
      af_[q_] = *(const s16x8*)(As_ + ((ra_ + (q_ << 4)) << 6) + xo);          \
      bf_[q_] = *(const s16x8*)(Bs_ + ((rb_ + (q_ << 4)) << 6) + xo);          \
    }                                                                          \
    STG_STMT;                                                                  \
    __builtin_amdgcn_sched_barrier(0);                                         \
    __builtin_amdgcn_s_barrier();                                              \
    asm volatile("s_waitcnt lgkmcnt(0)" ::: "memory");                         \
    __builtin_amdgcn_sched_barrier(0);                                         \
    __builtin_amdgcn_s_setprio(1);                                             \
    _Pragma("unroll")                                                          \
    for (int mi_ = 0; mi_ < 4; ++mi_) {                                        \
      _Pragma("unroll")                                                        \
      for (int nj_ = 0; nj_ < 4; ++nj_)                                        \
        acc[((MH)*4 + mi_) * 4 + nj_] = __builtin_amdgcn_mfma_f32_16x16x32_bf16( \
            af_[mi_], bf_[nj_], acc[((MH)*4 + mi_) * 4 + nj_], 0, 0, 0);       \
    }                                                                          \
    __builtin_amdgcn_s_setprio(0);                                             \
    __builtin_amdgcn_sched_barrier(0);                                         \
    VM_STMT;                                                                   \
    __builtin_amdgcn_s_barrier();                                              \
  }

  // prologue: 6 half-slot stages (tile0 full, tile1 k0-halves), 12 loads
  STG(0, 0, 0, 0)
  STG(0, 0, 1, 0)
  STG(0, 1, 0, 0)
  STG(0, 1, 1, 0)
  STG(1, 0, 0, 1)
  STG(1, 0, 1, 1)
  VMW(8);  // oldest 4 (buf0 ks0 A+B) complete
  __builtin_amdgcn_s_barrier();

  const int NI = NT >> 1;
  for (int it = 0; it < NI - 1; ++it) {
    const int t1 = 2 * it + 1, t2 = 2 * it + 2, t3 = 2 * it + 3;
    PHASE(0, 0, 0, STG(1, 1, 0, t1), )
    PHASE(0, 1, 0, STG(1, 1, 1, t1), VMW(6))
    PHASE(0, 0, 1, STG(0, 0, 0, t2), )
    PHASE(0, 1, 1, STG(0, 0, 1, t2), VMW(6))
    PHASE(1, 0, 0, STG(0, 1, 0, t2), )
    PHASE(1, 1, 0, STG(0, 1, 1, t2), VMW(6))
    PHASE(1, 0, 1, STG(1, 0, 0, t3), )
    PHASE(1, 1, 1, STG(1, 0, 1, t3), VMW(6))
  }
  // epilogue iteration: tiles NT-2 (buf0), NT-1 (buf1); stage only buf1 khalf1.
  // Drain: VMW(8) covers prev ph5-6 (buf0 ks1); VMW(4) covers prev ph7-8
  // (buf1 ks0); VMW(0) covers this iter's ph1-2 (buf1 ks1).
  {
    PHASE(0, 0, 0, STG(1, 1, 0, NT - 1), )
    PHASE(0, 1, 0, STG(1, 1, 1, NT - 1), VMW(8))
    PHASE(0, 0, 1, (void)0, )
    PHASE(0, 1, 1, (void)0, VMW(4))
    PHASE(1, 0, 0, (void)0, )
    PHASE(1, 1, 0, (void)0, VMW(0))
    PHASE(1, 0, 1, (void)0, )
    PHASE(1, 1, 1, (void)0, )
  }
#undef PHASE
#undef STG
#undef VMW

  const int gr0 = row0 + wm128;
  const int gc0 = col0 + wn64;
#pragma unroll
  for (int nj = 0; nj < 4; ++nj) {
    const int col = gc0 + (nj << 4) + lr;
    const float bv = (EPI != 0) ? bias[col] : 0.f;
#pragma unroll
    for (int mi = 0; mi < 8; ++mi) {
#pragma unroll
      for (int rg = 0; rg < 4; ++rg) {
        const int row = gr0 + (mi << 4) + (hi << 2) + rg;
        const size_t off = (size_t)row * N + col;
        float val = acc[mi * 4 + nj][rg] + bv;
        if constexpr (EPI == 2) val = fmaxf(val, 0.f);
        if constexpr (EPI == 0 || EPI == 2) Cb[off] = f2bf(val);
        else Cf[off] = val;
      }
    }
  }
}

// ---------------------------------------------------------------------------
// GEMM 128x128 (m97 structure): used for proj / FF2 (N=1024).
// EPI: 1 = f32 out + bias + residual(in-place Cf).
// ---------------------------------------------------------------------------
template <int EPI>
__global__ __launch_bounds__(256) void gemm_bt(
    const u16* __restrict__ A, const u16* __restrict__ Bt,
    const float* __restrict__ bias, float* Cf, u16* Cb,
    int M, int N, int K) {
  __shared__ u16 lds[2][2][4096];  // [buf][A/B][128*32] = 32 KiB
  const int tid = threadIdx.x;
  const int lane = tid & 63;
  const int lr = lane & 15, hi = lane >> 4;
  const int wid = tid >> 6;
  const int wm = wid >> 1, wn = wid & 1;
  const int row0 = blockIdx.y << 7, col0 = blockIdx.x << 7;
  const int NT = K >> 5;
  const int wbase = (tid & ~63) << 4;

  f32x4 acc[4][4];
#pragma unroll
  for (int i = 0; i < 4; ++i)
#pragma unroll
    for (int j = 0; j < 4; ++j) acc[i][j] = f32x4{0.f, 0.f, 0.f, 0.f};

  auto stage = [&](int buf, int kt) {
#pragma unroll
    for (int c = 0; c < 2; ++c) {
      const int o = (c << 12) + (tid << 4);
      const int r = o >> 6;
      const int il = (o & 63) ^ ((r & 3) << 4);
      gld16(A + (size_t)(row0 + r) * K + (kt << 5) + (il >> 1),
            (char*)&lds[buf][0][0] + (c << 12) + wbase);
      gld16(Bt + (size_t)(col0 + r) * K + (kt << 5) + (il >> 1),
            (char*)&lds[buf][1][0] + (c << 12) + wbase);
    }
  };

  stage(0, 0);
  __syncthreads();
  int cur = 0;
  for (int kt = 0; kt < NT; ++kt) {
    if (kt + 1 < NT) stage(cur ^ 1, kt + 1);
    const char* As = (const char*)&lds[cur][0][0];
    const char* Bs = (const char*)&lds[cur][1][0];
    s16x8 af[4], bfr[4];
#pragma unroll
    for (int i = 0; i < 4; ++i) {
      const int ra = (wm << 6) + (i << 4) + lr;
      af[i] = *(const s16x8*)(As + (ra << 6) + (((hi ^ (ra & 3)) & 3) << 4));
      const int rb = (wn << 6) + (i << 4) + lr;
      bfr[i] = *(const s16x8*)(Bs + (rb << 6) + (((hi ^ (rb & 3)) & 3) << 4));
    }
#pragma unroll
    for (int i = 0; i < 4; ++i)
#pragma unroll
      for (int j = 0; j < 4; ++j)
        acc[i][j] =
            __builtin_amdgcn_mfma_f32_16x16x32_bf16(af[i], bfr[j], acc[i][j], 0, 0, 0);
    __syncthreads();
    cur ^= 1;
  }

  const int gr = row0 + (wm << 6);
  const int gc = col0 + (wn << 6);
#pragma unroll
  for (int j = 0; j < 4; ++j) {
    const int col = gc + (j << 4) + lr;
    const float bv = (EPI != 0) ? bias[col] : 0.f;
#pragma unroll
    for (int i = 0; i < 4; ++i) {
#pragma unroll
      for (int rg = 0; rg < 4; ++rg) {
        const int row = gr + (i << 4) + (hi << 2) + rg;
        const size_t off = (size_t)row * N + col;
        float val = acc[i][j][rg] + bv;
        if constexpr (EPI == 1) val += Cf[off];
        if constexpr (EPI == 2) val = fmaxf(val, 0.f);
        if constexpr (EPI == 0 || EPI == 2) Cb[off] = f2bf(val);
        else Cf[off] = val;
      }
    }
  }
}

// ---------------------------------------------------------------------------
// LayerNorm over D=1024, f32 in -> bf16 out. One block per row.
// ---------------------------------------------------------------------------
__global__ __launch_bounds__(256) void ln_kernel(const float* __restrict__ x,
                                                 const float* __restrict__ gw,
                                                 const float* __restrict__ bw,
                                                 u16* __restrict__ out) {
  const int r = blockIdx.x, tid = threadIdx.x;
  const int lane = tid & 63, wid = tid >> 6;
  __shared__ float red[8];
  f32x4 v = *(const f32x4*)(x + ((size_t)r << 10) + (tid << 2));
  float s = v[0] + v[1] + v[2] + v[3];
  float q = v[0] * v[0] + v[1] * v[1] + v[2] * v[2] + v[3] * v[3];
#pragma unroll
  for (int off = 32; off; off >>= 1) {
    s += __shfl_down(s, off);
    q += __shfl_down(q, off);
  }
  if (lane == 0) {
    red[wid] = s;
    red[4 + wid] = q;
  }
  __syncthreads();
  const float mean = (red[0] + red[1] + red[2] + red[3]) * (1.f / 1024.f);
  const float var = (red[4] + red[5] + red[6] + red[7]) * (1.f / 1024.f) - mean * mean;
  const float rstd = rsqrtf(var + 1e-5f);
  f32x4 g4 = *(const f32x4*)(gw + (tid << 2));
  f32x4 b4 = *(const f32x4*)(bw + (tid << 2));
  u16* op = out + ((size_t)r << 10) + (tid << 2);
#pragma unroll
  for (int j = 0; j < 4; ++j) op[j] = f2bf((v[j] - mean) * rstd * g4[j] + b4[j]);
}

// ---------------------------------------------------------------------------
// Embedding: x[r] = tok_emb[idx[r]] + pos_emb[r % T]
// ---------------------------------------------------------------------------
__global__ __launch_bounds__(256) void embed_kernel(const int* __restrict__ idx,
                                                    const float* __restrict__ tok,
                                                    const float* __restrict__ pos,
                                                    float* __restrict__ x) {
  const int r = blockIdx.x, tid = threadIdx.x;
  const int t = r & (T_ - 1);
  const int tk = idx[r];
  f32x4 a = *(const f32x4*)(tok + ((size_t)tk << 10) + (tid << 2));
  f32x4 p = *(const f32x4*)(pos + ((size_t)t << 10) + (tid << 2));
  *(f32x4*)(x + ((size_t)r << 10) + (tid << 2)) = a + p;
}

// ---------------------------------------------------------------------------
// Transpose + f32->bf16: src [K][N] f32 -> dst [N][K] bf16. 32x32 LDS tiles.
// ---------------------------------------------------------------------------
__global__ __launch_bounds__(256) void tconv_kernel(const float* __restrict__ src,
                                                    u16* __restrict__ dst, int K, int N) {
  __shared__ float tile[32][33];
  const int tx = threadIdx.x & 31, ty = threadIdx.x >> 5;
  const int n0 = blockIdx.x << 5, k0 = blockIdx.y << 5;
#pragma unroll
  for (int i = 0; i < 32; i += 8)
    tile[ty + i][tx] = src[(size_t)(k0 + ty + i) * N + n0 + tx];
  __syncthreads();
#pragma unroll
  for (int i = 0; i < 32; i += 8)
    dst[(size_t)(n0 + ty + i) * K + k0 + tx] = f2bf(tile[tx][ty + i]);
}

// ---------------------------------------------------------------------------
// Flash attention (causal). qkv bf16 [B*T][3072] (q|k|v, each h*64+hs).
// Block = 4 waves, one 64-row q-tile of one (b,h). Each wave: 16 q-rows.
// ---------------------------------------------------------------------------
__global__ __launch_bounds__(256) void fattn_kernel(const u16* __restrict__ qkv,
                                                    u16* __restrict__ o) {
  const int qt = blockIdx.x, h = blockIdx.y, b = blockIdx.z;
  const int tid = threadIdx.x;
  const int lane = tid & 63;
  const int lr = lane & 15, hi = lane >> 4;
  const int w = tid >> 6;
  __shared__ u16 Kl[4096];      // [kv][64 d], 128B rows, chunk-swizzled
  __shared__ u16 Vt[4096];      // [d][64 kv], 128B rows, chunk-swizzled
  __shared__ u16 Pl[4][1024];   // per-wave P [16 q][64 kv], chunk-swizzled

  const int q_row = (qt << 6) + (w << 4) + lr;
  const size_t qbase = ((size_t)(b * T_) + q_row) * 3072 + (h << 6);
  s16x8 aq[2];
  aq[0] = *(const s16x8*)(qkv + qbase + hi * 8);
  aq[1] = *(const s16x8*)(qkv + qbase + 32 + hi * 8);

  f32x4 ofr[4];
  float m[4], lsum[4];
#pragma unroll
  for (int j = 0; j < 4; ++j) ofr[j] = f32x4{0.f, 0.f, 0.f, 0.f};
#pragma unroll
  for (int rg = 0; rg < 4; ++rg) { m[rg] = -1e30f; lsum[rg] = 0.f; }

  const size_t bT = (size_t)(b * T_);

  for (int kt = 0; kt <= qt; ++kt) {
    const int kv0 = kt << 6;
#pragma unroll
    for (int sh = 0; sh < 2; ++sh) {
      const int ob = (sh << 12) + (tid << 4);
      const int r = ob >> 7;
      const int il = (ob & 127) ^ ((r & 7) << 4);
      gld16(qkv + (bT + kv0 + r) * 3072 + 1024 + (h << 6) + (il >> 1),
            (char*)Kl + (sh << 12) + ((tid & 192) << 4));
    }
#pragma unroll
    for (int sh = 0; sh < 2; ++sh) {
      const int c = (w << 1) + sh;
      uint4 pv = *(const uint4*)(qkv + (bT + kv0 + lane) * 3072 + 2048 +
                                 (h << 6) + (c << 3));
#pragma unroll
      for (int j = 0; j < 8; ++j) {
        const int d = (c << 3) + j;
        Vt[(d << 6) + (lane ^ ((d & 7) << 3))] = ((const u16*)&pv)[j];
      }
    }
    __syncthreads();

    f32x4 s[4];
#pragma unroll
    for (int j = 0; j < 4; ++j) s[j] = f32x4{0.f, 0.f, 0.f, 0.f};
#pragma unroll
    for (int kk = 0; kk < 2; ++kk)
#pragma unroll
      for (int j = 0; j < 4; ++j) {
        const int rb = (j << 4) + lr;
        const s16x8 bk = *(const s16x8*)((const char*)Kl + (rb << 7) +
                                         ((((kk << 2) + hi) ^ (rb & 7)) << 4));
        s[j] = __builtin_amdgcn_mfma_f32_16x16x32_bf16(aq[kk], bk, s[j], 0, 0, 0);
      }

    const bool diag = (kt == qt);
#pragma unroll
    for (int j = 0; j < 4; ++j) {
      f32x4 sv = s[j] * 0.125f;
      if (diag) {
        const int col = (j << 4) + lr;
#pragma unroll
        for (int rg = 0; rg < 4; ++rg) {
          const int row = (w << 4) + (hi << 2) + rg;
          if (col > row) sv[rg] = -1e30f;
        }
      }
      s[j] = sv;
    }

#pragma unroll
    for (int rg = 0; rg < 4; ++rg) {
      float mx = fmaxf(fmaxf(s[0][rg], s[1][rg]), fmaxf(s[2][rg], s[3][rg]));
      mx = fmaxf(mx, __shfl_xor(mx, 1));
      mx = fmaxf(mx, __shfl_xor(mx, 2));
      mx = fmaxf(mx, __shfl_xor(mx, 4));
      mx = fmaxf(mx, __shfl_xor(mx, 8));
      const float mn = fmaxf(m[rg], mx);
      const float sc = __expf(m[rg] - mn);
      m[rg] = mn;
      float rs = 0.f;
#pragma unroll
      for (int j = 0; j < 4; ++j) {
        const float e = __expf(s[j][rg] - mn);
        s[j][rg] = e;
        rs += e;
      }
      rs += __shfl_xor(rs, 1);
      rs += __shfl_xor(rs, 2);
      rs += __shfl_xor(rs, 4);
      rs += __shfl_xor(rs, 8);
      lsum[rg] = lsum[rg] * sc + rs;
#pragma unroll
      for (int j2 = 0; j2 < 4; ++j2) ofr[j2][rg] *= sc;
    }

#pragma unroll
    for (int j = 0; j < 4; ++j)
#pragma unroll
      for (int rg = 0; rg < 4; ++rg) {
        const int row = (hi << 2) + rg, col = (j << 4) + lr;
        Pl[w][(row << 6) + (col ^ ((row & 7) << 3))] = f2bf(s[j][rg]);
      }

#pragma unroll
    for (int kk = 0; kk < 2; ++kk) {
      const s16x8 ap = *(const s16x8*)((const char*)&Pl[w][0] + (lr << 7) +
                                       (((kk << 6) + (hi << 4)) ^ ((lr & 7) << 4)));
#pragma unroll
      for (int j2 = 0; j2 < 4; ++j2) {
        const int rb = (j2 << 4) + lr;
        const s16x8 bv = *(const s16x8*)((const char*)Vt + (rb << 7) +
                                         ((((kk << 2) + hi) ^ (rb & 7)) << 4));
        ofr[j2] = __builtin_amdgcn_mfma_f32_16x16x32_bf16(ap, bv, ofr[j2], 0, 0, 0);
      }
    }
    __syncthreads();
  }

  float rinv[4];
#pragma unroll
  for (int rg = 0; rg < 4; ++rg) rinv[rg] = 1.f / lsum[rg];
#pragma unroll
  for (int j2 = 0; j2 < 4; ++j2)
#pragma unroll
    for (int rg = 0; rg < 4; ++rg) {
      const int row = (qt << 6) + (w << 4) + (hi << 2) + rg;
      const int col = (h << 6) + (j2 << 4) + lr;
      o[(bT + row) * 1024 + col] = f2bf(ofr[j2][rg] * rinv[rg]);
    }
}

// ---------------------------------------------------------------------------
extern "C" void kernel_launch(void* const* d_in, const int* in_sizes, int n_in,
                              void* d_out, int out_size, void* d_ws, size_t ws_size,
                              hipStream_t stream) {
  (void)in_sizes; (void)n_in; (void)out_size; (void)ws_size;
  const int* idx = (const int*)d_in[0];
  const float* tokE = (const float*)d_in[1];
  const float* posE = (const float*)d_in[2];
  const float* Wq = (const float*)d_in[3];
  const float* Wk = (const float*)d_in[4];
  const float* Wv = (const float*)d_in[5];
  const float* Wp = (const float*)d_in[6];
  const float* bp = (const float*)d_in[7];
  const float* ln1g = (const float*)d_in[8];
  const float* ln1b = (const float*)d_in[9];
  const float* ln2g = (const float*)d_in[10];
  const float* ln2b = (const float*)d_in[11];
  const float* W1 = (const float*)d_in[12];
  const float* b1 = (const float*)d_in[13];
  const float* W2 = (const float*)d_in[14];
  const float* b2 = (const float*)d_in[15];
  const float* lnfg = (const float*)d_in[16];
  const float* lnfb = (const float*)d_in[17];
  const float* Wlm = (const float*)d_in[18];
  const float* blm = (const float*)d_in[19];

  char* p = (char*)d_ws;
  float* x = (float*)p;   p += (size_t)BT_ * D_ * 4;
  u16* xn = (u16*)p;      p += (size_t)BT_ * D_ * 2;
  u16* qkv = (u16*)p;     p += (size_t)BT_ * 3072 * 2;
  u16* ob = (u16*)p;      p += (size_t)BT_ * D_ * 2;
  u16* hb = (u16*)p;      p += (size_t)BT_ * FF_ * 2;
  u16* WqkvT = (u16*)p;   p += (size_t)L_ * 3072 * D_ * 2;
  u16* WpT = (u16*)p;     p += (size_t)L_ * D_ * D_ * 2;
  u16* W1T = (u16*)p;     p += (size_t)L_ * FF_ * D_ * 2;
  u16* W2T = (u16*)p;     p += (size_t)L_ * D_ * FF_ * 2;
  u16* WlmT = (u16*)p;    p += (size_t)V_ * D_ * 2;

  dim3 blk(256);
  dim3 blk512(512);
  // weight convert+transpose (bf16, [N][K]) — every call (no caching allowed)
  for (int l = 0; l < L_; ++l) {
    tconv_kernel<<<dim3(32, 32), blk, 0, stream>>>(Wq + (size_t)l * D_ * D_,
                                                   WqkvT + (size_t)l * 3072 * D_, D_, D_);
    tconv_kernel<<<dim3(32, 32), blk, 0, stream>>>(
        Wk + (size_t)l * D_ * D_, WqkvT + (size_t)l * 3072 * D_ + D_ * D_, D_, D_);
    tconv_kernel<<<dim3(32, 32), blk, 0, stream>>>(
        Wv + (size_t)l * D_ * D_, WqkvT + (size_t)l * 3072 * D_ + 2 * D_ * D_, D_, D_);
    tconv_kernel<<<dim3(32, 32), blk, 0, stream>>>(Wp + (size_t)l * D_ * D_,
                                                   WpT + (size_t)l * D_ * D_, D_, D_);
    tconv_kernel<<<dim3(128, 32), blk, 0, stream>>>(W1 + (size_t)l * D_ * FF_,
                                                    W1T + (size_t)l * FF_ * D_, D_, FF_);
    tconv_kernel<<<dim3(32, 128), blk, 0, stream>>>(W2 + (size_t)l * FF_ * D_,
                                                    W2T + (size_t)l * D_ * FF_, FF_, D_);
  }
  tconv_kernel<<<dim3(1000, 32), blk, 0, stream>>>(Wlm, WlmT, D_, V_);

  embed_kernel<<<dim3(BT_), blk, 0, stream>>>(idx, tokE, posE, x);

  for (int l = 0; l < L_; ++l) {
    ln_kernel<<<dim3(BT_), blk, 0, stream>>>(x, ln1g + l * D_, ln1b + l * D_, xn);
    gemm256<0><<<dim3(192), blk512, 0, stream>>>(xn, WqkvT + (size_t)l * 3072 * D_,
                                                 nullptr, nullptr, qkv, BT_, 3072, D_, 16);
    fattn_kernel<<<dim3(T_ / 64, H_, B_), blk, 0, stream>>>(qkv, ob);
    gemm_bt<1><<<dim3(8, 32), blk, 0, stream>>>(ob, WpT + (size_t)l * D_ * D_,
                                                bp + l * D_, x, nullptr, BT_, D_, D_);
    ln_kernel<<<dim3(BT_), blk, 0, stream>>>(x, ln2g + l * D_, ln2b + l * D_, xn);
    gemm256<2><<<dim3(256), blk512, 0, stream>>>(xn, W1T + (size_t)l * FF_ * D_,
                                                 b1 + l * FF_, nullptr, hb, BT_, FF_, D_, 16);
    gemm_bt<1><<<dim3(8, 32), blk, 0, stream>>>(hb, W2T + (size_t)l * D_ * FF_,
                                                b2 + l * D_, x, nullptr, BT_, D_, FF_);
  }
  ln_kernel<<<dim3(BT_), blk, 0, stream>>>(x, lnfg, lnfb, xn);
  gemm256<3><<<dim3(2000), blk512, 0, stream>>>(xn, WlmT, blm, (float*)d_out, nullptr,
                                                BT_, V_, D_, 16);
}

// Round 5
// 3047.591 us; speedup vs baseline: 1.0340x; 1.0340x over previous
//
#include <hip/hip_runtime.h>
#include <cstdint>

typedef __attribute__((ext_vector_type(4))) float f32x4;
typedef __attribute__((ext_vector_type(8))) short s16x8;
typedef unsigned short u16;
typedef unsigned int u32;
typedef __attribute__((address_space(1))) void gas_void;
typedef __attribute__((address_space(3))) void las_void;

#define B_ 4
#define T_ 1024
#define V_ 32000
#define D_ 1024
#define H_ 16
#define HS_ 64
#define FF_ 4096
#define L_ 8
#define BT_ (B_ * T_)

__device__ __forceinline__ float bf2f(u16 h) { return __uint_as_float(((u32)h) << 16); }
__device__ __forceinline__ u16 f2bf(float f) {
  u32 u = __float_as_uint(f);
  u += 0x7fffu + ((u >> 16) & 1u);
  return (u16)(u >> 16);
}

// async global->LDS, 16B per lane; lds dest must be wave-uniform base (+lane*16 by HW)
__device__ __forceinline__ void gld16(const void* g, void* l) {
  __builtin_amdgcn_global_load_lds((gas_void*)(uintptr_t)g,
                                   (las_void*)(u32)(uintptr_t)l, 16, 0, 0);
}

// LDS 64B-row tiles: physical chunk c holds logical k-chunk l = (c - (row>>1))&3.
// Read side: c = (l + (row>>1))&3 -> per-16-lane group every (parity,chunk)
// cell is hit exactly 2x = conflict-free (2-way is free, m136).

// ---------------------------------------------------------------------------
// gemm256: C[M,N] = A[M,K] @ Bt^T.  256x256 tile, BK=64, 8 waves (2Mx4N),
// 8-phase schedule w/ counted vmcnt (T3+T4), setprio (T5), XCD swizzle (T1).
// B-fragments loaded on odd phases, reused from registers on even phases.
// Requires M%256==0, N%256==0, K%128==0, K>=256, grid%8==0.
// EPI: 0 = bf16 out; 2 = bf16 + bias + relu; 3 = f32 + bias.
// ---------------------------------------------------------------------------
template <int EPI>
__global__ __launch_bounds__(512, 2) void gemm256(
    const u16* __restrict__ A, const u16* __restrict__ Bt,
    const float* __restrict__ bias, float* Cf, u16* Cb,
    int M, int N, int K, int nrowb) {
  __shared__ u16 lds[2][2][2][8192];  // [buf][khalf][A/B][256*32] = 128 KiB
  const int tid = threadIdx.x;
  const int lane = tid & 63;
  const int lr = lane & 15, hi = lane >> 4;
  const int wid = tid >> 6;
  const int wm128 = (wid >> 2) << 7;
  const int wn64 = (wid & 3) << 6;
  const int logical = ((int)blockIdx.x & 7) * ((int)gridDim.x >> 3) + ((int)blockIdx.x >> 3);
  const int row0 = (logical % nrowb) << 8;
  const int col0 = (logical / nrowb) << 8;
  const int NT = K >> 6;
  const int srow = tid >> 2;   // staging row within 8KB shot
  const int schunk = tid & 3;  // staging dest 16B chunk
  const int xo = ((hi + (lr >> 1)) & 3) << 4;  // frag-read swizzle byte offset

  f32x4 acc[32];
#pragma unroll
  for (int i = 0; i < 32; ++i) acc[i] = f32x4{0.f, 0.f, 0.f, 0.f};
  s16x8 bfr[4];  // B fragments persist across phase pairs

#define VMW(N) asm volatile("s_waitcnt vmcnt(" #N ")" ::: "memory")

#define STG(DB, DK, OP, KT)                                                    \
  {                                                                            \
    const u16* sp_ = (OP) ? Bt : A;                                            \
    const int base_ = (OP) ? col0 : row0;                                      \
    const int c0_ = ((KT) << 6) + ((DK) << 5);                                 \
    _Pragma("unroll")                                                          \
    for (int sh_ = 0; sh_ < 2; ++sh_) {                                        \
      const int rr_ = (sh_ << 7) + srow;                                       \
      const int ko_ = ((schunk - (rr_ >> 1)) & 3) << 3;                        \
      gld16(sp_ + (size_t)(base_ + rr_) * K + c0_ + ko_,                       \
            (char*)&lds[DB][DK][OP][0] + (sh_ << 13) + (wid << 10));           \
    }                                                                          \
  }

#define PHASE(BUF, MH, KS, LOADB, STG_STMT, VM_STMT)                           \
  {                                                                            \
    __builtin_amdgcn_sched_barrier(0);                                         \
    const char* As_ = (const char*)&lds[BUF][KS][0][0];                        \
    const char* Bs_ = (const char*)&lds[BUF][KS][1][0];                        \
    const int ra_ = wm128 + ((MH) << 6) + lr;                                  \
    s16x8 af_[4];                                                              \
    _Pragma("unroll")                                                          \
    for (int q_ = 0; q_ < 4; ++q_)                                             \
      af_[q_] = *(const s16x8*)(As_ + ((ra_ + (q_ << 4)) << 6) + xo);          \
    if (LOADB) {                                                               \
      _Pragma("unroll")                                                        \
      for (int q_ = 0; q_ < 4; ++q_)                                           \
        bfr[q_] = *(const s16x8*)(Bs_ + ((wn64 + lr + (q_ << 4)) << 6) + xo);  \
    }                                                                          \
    STG_STMT;                                                                  \
    __builtin_amdgcn_sched_barrier(0);                                         \
    __builtin_amdgcn_s_barrier();                                              \
    asm volatile("s_waitcnt lgkmcnt(0)" ::: "memory");                         \
    __builtin_amdgcn_sched_barrier(0);                                         \
    __builtin_amdgcn_s_setprio(1);                                             \
    _Pragma("unroll")                                                          \
    for (int mi_ = 0; mi_ < 4; ++mi_) {                                        \
      _Pragma("unroll")                                                        \
      for (int nj_ = 0; nj_ < 4; ++nj_)                                        \
        acc[((MH)*4 + mi_) * 4 + nj_] = __builtin_amdgcn_mfma_f32_16x16x32_bf16( \
            af_[mi_], bfr[nj_], acc[((MH)*4 + mi_) * 4 + nj_], 0, 0, 0);       \
    }                                                                          \
    __builtin_amdgcn_s_setprio(0);                                             \
    __builtin_amdgcn_sched_barrier(0);                                         \
    VM_STMT;                                                                   \
    __builtin_amdgcn_s_barrier();                                              \
  }

  // prologue: 6 half-slot stages (tile0 full, tile1 k0-halves), 12 loads
  STG(0, 0, 0, 0)
  STG(0, 0, 1, 0)
  STG(0, 1, 0, 0)
  STG(0, 1, 1, 0)
  STG(1, 0, 0, 1)
  STG(1, 0, 1, 1)
  VMW(8);  // oldest 4 (buf0 ks0 A+B) complete
  __builtin_amdgcn_s_barrier();

  const int NI = NT >> 1;
  for (int it = 0; it < NI - 1; ++it) {
    const int t1 = 2 * it + 1, t2 = 2 * it + 2, t3 = 2 * it + 3;
    PHASE(0, 0, 0, 1, STG(1, 1, 0, t1), )
    PHASE(0, 1, 0, 0, STG(1, 1, 1, t1), VMW(6))
    PHASE(0, 0, 1, 1, STG(0, 0, 0, t2), )
    PHASE(0, 1, 1, 0, STG(0, 0, 1, t2), VMW(6))
    PHASE(1, 0, 0, 1, STG(0, 1, 0, t2), )
    PHASE(1, 1, 0, 0, STG(0, 1, 1, t2), VMW(6))
    PHASE(1, 0, 1, 1, STG(1, 0, 0, t3), )
    PHASE(1, 1, 1, 0, STG(1, 0, 1, t3), VMW(6))
  }
  // epilogue iteration: tiles NT-2 (buf0), NT-1 (buf1); stage only buf1 khalf1.
  // Drain: VMW(8) covers prev ph5-6 (buf0 ks1); VMW(4) covers prev ph7-8
  // (buf1 ks0); VMW(0) covers this iter's ph1-2 (buf1 ks1).
  {
    PHASE(0, 0, 0, 1, STG(1, 1, 0, NT - 1), )
    PHASE(0, 1, 0, 0, STG(1, 1, 1, NT - 1), VMW(8))
    PHASE(0, 0, 1, 1, (void)0, )
    PHASE(0, 1, 1, 0, (void)0, VMW(4))
    PHASE(1, 0, 0, 1, (void)0, )
    PHASE(1, 1, 0, 0, (void)0, VMW(0))
    PHASE(1, 0, 1, 1, (void)0, )
    PHASE(1, 1, 1, 0, (void)0, )
  }
#undef PHASE
#undef STG
#undef VMW

  const int gr0 = row0 + wm128;
  const int gc0 = col0 + wn64;
#pragma unroll
  for (int nj = 0; nj < 4; ++nj) {
    const int col = gc0 + (nj << 4) + lr;
    const float bv = (EPI != 0) ? bias[col] : 0.f;
#pragma unroll
    for (int mi = 0; mi < 8; ++mi) {
#pragma unroll
      for (int rg = 0; rg < 4; ++rg) {
        const int row = gr0 + (mi << 4) + (hi << 2) + rg;
        const size_t off = (size_t)row * N + col;
        float val = acc[mi * 4 + nj][rg] + bv;
        if constexpr (EPI == 2) val = fmaxf(val, 0.f);
        if constexpr (EPI == 0 || EPI == 2) Cb[off] = f2bf(val);
        else Cf[off] = val;
      }
    }
  }
}

// ---------------------------------------------------------------------------
// GEMM 128x128 (m97 structure): used for proj / FF2 (N=1024).
// EPI: 1 = f32 out + bias + residual(in-place Cf).
// ---------------------------------------------------------------------------
template <int EPI>
__global__ __launch_bounds__(256) void gemm_bt(
    const u16* __restrict__ A, const u16* __restrict__ Bt,
    const float* __restrict__ bias, float* Cf, u16* Cb,
    int M, int N, int K) {
  __shared__ u16 lds[2][2][4096];  // [buf][A/B][128*32] = 32 KiB
  const int tid = threadIdx.x;
  const int lane = tid & 63;
  const int lr = lane & 15, hi = lane >> 4;
  const int wid = tid >> 6;
  const int wm = wid >> 1, wn = wid & 1;
  const int row0 = blockIdx.y << 7, col0 = blockIdx.x << 7;
  const int NT = K >> 5;
  const int wbase = (tid & ~63) << 4;
  const int xo = ((hi + (lr >> 1)) & 3) << 4;

  f32x4 acc[4][4];
#pragma unroll
  for (int i = 0; i < 4; ++i)
#pragma unroll
    for (int j = 0; j < 4; ++j) acc[i][j] = f32x4{0.f, 0.f, 0.f, 0.f};

  auto stage = [&](int buf, int kt) {
#pragma unroll
    for (int c = 0; c < 2; ++c) {
      const int o = (c << 12) + (tid << 4);
      const int r = o >> 6;
      const int ko = ((((o >> 4) & 3) - (r >> 1)) & 3) << 3;  // logical k elems
      gld16(A + (size_t)(row0 + r) * K + (kt << 5) + ko,
            (char*)&lds[buf][0][0] + (c << 12) + wbase);
      gld16(Bt + (size_t)(col0 + r) * K + (kt << 5) + ko,
            (char*)&lds[buf][1][0] + (c << 12) + wbase);
    }
  };

  stage(0, 0);
  __syncthreads();
  int cur = 0;
  for (int kt = 0; kt < NT; ++kt) {
    if (kt + 1 < NT) stage(cur ^ 1, kt + 1);
    const char* As = (const char*)&lds[cur][0][0];
    const char* Bs = (const char*)&lds[cur][1][0];
    s16x8 af[4], bfr[4];
#pragma unroll
    for (int i = 0; i < 4; ++i) {
      const int ra = (wm << 6) + (i << 4) + lr;
      af[i] = *(const s16x8*)(As + (ra << 6) + xo);
      const int rb = (wn << 6) + (i << 4) + lr;
      bfr[i] = *(const s16x8*)(Bs + (rb << 6) + xo);
    }
#pragma unroll
    for (int i = 0; i < 4; ++i)
#pragma unroll
      for (int j = 0; j < 4; ++j)
        acc[i][j] =
            __builtin_amdgcn_mfma_f32_16x16x32_bf16(af[i], bfr[j], acc[i][j], 0, 0, 0);
    __syncthreads();
    cur ^= 1;
  }

  const int gr = row0 + (wm << 6);
  const int gc = col0 + (wn << 6);
#pragma unroll
  for (int j = 0; j < 4; ++j) {
    const int col = gc + (j << 4) + lr;
    const float bv = (EPI != 0) ? bias[col] : 0.f;
#pragma unroll
    for (int i = 0; i < 4; ++i) {
#pragma unroll
      for (int rg = 0; rg < 4; ++rg) {
        const int row = gr + (i << 4) + (hi << 2) + rg;
        const size_t off = (size_t)row * N + col;
        float val = acc[i][j][rg] + bv;
        if constexpr (EPI == 1) val += Cf[off];
        if constexpr (EPI == 2) val = fmaxf(val, 0.f);
        if constexpr (EPI == 0 || EPI == 2) Cb[off] = f2bf(val);
        else Cf[off] = val;
      }
    }
  }
}

// ---------------------------------------------------------------------------
// LayerNorm over D=1024, f32 in -> bf16 out. One block per row.
// ---------------------------------------------------------------------------
__global__ __launch_bounds__(256) void ln_kernel(const float* __restrict__ x,
                                                 const float* __restrict__ gw,
                                                 const float* __restrict__ bw,
                                                 u16* __restrict__ out) {
  const int r = blockIdx.x, tid = threadIdx.x;
  const int lane = tid & 63, wid = tid >> 6;
  __shared__ float red[8];
  f32x4 v = *(const f32x4*)(x + ((size_t)r << 10) + (tid << 2));
  float s = v[0] + v[1] + v[2] + v[3];
  float q = v[0] * v[0] + v[1] * v[1] + v[2] * v[2] + v[3] * v[3];
#pragma unroll
  for (int off = 32; off; off >>= 1) {
    s += __shfl_down(s, off);
    q += __shfl_down(q, off);
  }
  if (lane == 0) {
    red[wid] = s;
    red[4 + wid] = q;
  }
  __syncthreads();
  const float mean = (red[0] + red[1] + red[2] + red[3]) * (1.f / 1024.f);
  const float var = (red[4] + red[5] + red[6] + red[7]) * (1.f / 1024.f) - mean * mean;
  const float rstd = rsqrtf(var + 1e-5f);
  f32x4 g4 = *(const f32x4*)(gw + (tid << 2));
  f32x4 b4 = *(const f32x4*)(bw + (tid << 2));
  u16* op = out + ((size_t)r << 10) + (tid << 2);
#pragma unroll
  for (int j = 0; j < 4; ++j) op[j] = f2bf((v[j] - mean) * rstd * g4[j] + b4[j]);
}

// ---------------------------------------------------------------------------
// Embedding: x[r] = tok_emb[idx[r]] + pos_emb[r % T]
// ---------------------------------------------------------------------------
__global__ __launch_bounds__(256) void embed_kernel(const int* __restrict__ idx,
                                                    const float* __restrict__ tok,
                                                    const float* __restrict__ pos,
                                                    float* __restrict__ x) {
  const int r = blockIdx.x, tid = threadIdx.x;
  const int t = r & (T_ - 1);
  const int tk = idx[r];
  f32x4 a = *(const f32x4*)(tok + ((size_t)tk << 10) + (tid << 2));
  f32x4 p = *(const f32x4*)(pos + ((size_t)t << 10) + (tid << 2));
  *(f32x4*)(x + ((size_t)r << 10) + (tid << 2)) = a + p;
}

// ---------------------------------------------------------------------------
// Transpose + f32->bf16: src [K][N] f32 -> dst [N][K] bf16. 32x32 LDS tiles.
// ---------------------------------------------------------------------------
__global__ __launch_bounds__(256) void tconv_kernel(const float* __restrict__ src,
                                                    u16* __restrict__ dst, int K, int N) {
  __shared__ float tile[32][33];
  const int tx = threadIdx.x & 31, ty = threadIdx.x >> 5;
  const int n0 = blockIdx.x << 5, k0 = blockIdx.y << 5;
#pragma unroll
  for (int i = 0; i < 32; i += 8)
    tile[ty + i][tx] = src[(size_t)(k0 + ty + i) * N + n0 + tx];
  __syncthreads();
#pragma unroll
  for (int i = 0; i < 32; i += 8)
    dst[(size_t)(n0 + ty + i) * K + k0 + tx] = f2bf(tile[tx][ty + i]);
}

// ---------------------------------------------------------------------------
// Flash attention (causal). qkv bf16 [B*T][3072] (q|k|v, each h*64+hs).
// Block = 4 waves, one 64-row q-tile of one (b,h). Each wave: 16 q-rows.
// ---------------------------------------------------------------------------
__global__ __launch_bounds__(256) void fattn_kernel(const u16* __restrict__ qkv,
                                                    u16* __restrict__ o) {
  const int qt = blockIdx.x, h = blockIdx.y, b = blockIdx.z;
  const int tid = threadIdx.x;
  const int lane = tid & 63;
  const int lr = lane & 15, hi = lane >> 4;
  const int w = tid >> 6;
  __shared__ u16 Kl[4096];      // [kv][64 d], 128B rows, chunk-swizzled
  __shared__ u16 Vt[4096];      // [d][64 kv], 128B rows, chunk-swizzled
  __shared__ u16 Pl[4][1024];   // per-wave P [16 q][64 kv], chunk-swizzled

  const int q_row = (qt << 6) + (w << 4) + lr;
  const size_t qbase = ((size_t)(b * T_) + q_row) * 3072 + (h << 6);
  s16x8 aq[2];
  aq[0] = *(const s16x8*)(qkv + qbase + hi * 8);
  aq[1] = *(const s16x8*)(qkv + qbase + 32 + hi * 8);

  f32x4 ofr[4];
  float m[4], lsum[4];
#pragma unroll
  for (int j = 0; j < 4; ++j) ofr[j] = f32x4{0.f, 0.f, 0.f, 0.f};
#pragma unroll
  for (int rg = 0; rg < 4; ++rg) { m[rg] = -1e30f; lsum[rg] = 0.f; }

  const size_t bT = (size_t)(b * T_);

  for (int kt = 0; kt <= qt; ++kt) {
    const int kv0 = kt << 6;
#pragma unroll
    for (int sh = 0; sh < 2; ++sh) {
      const int ob = (sh << 12) + (tid << 4);
      const int r = ob >> 7;
      const int il = (ob & 127) ^ ((r & 7) << 4);
      gld16(qkv + (bT + kv0 + r) * 3072 + 1024 + (h << 6) + (il >> 1),
            (char*)Kl + (sh << 12) + ((tid & 192) << 4));
    }
#pragma unroll
    for (int sh = 0; sh < 2; ++sh) {
      const int c = (w << 1) + sh;
      uint4 pv = *(const uint4*)(qkv + (bT + kv0 + lane) * 3072 + 2048 +
                                 (h << 6) + (c << 3));
#pragma unroll
      for (int j = 0; j < 8; ++j) {
        const int d = (c << 3) + j;
        Vt[(d << 6) + (lane ^ ((d & 7) << 3))] = ((const u16*)&pv)[j];
      }
    }
    __syncthreads();

    f32x4 s[4];
#pragma unroll
    for (int j = 0; j < 4; ++j) s[j] = f32x4{0.f, 0.f, 0.f, 0.f};
#pragma unroll
    for (int kk = 0; kk < 2; ++kk)
#pragma unroll
      for (int j = 0; j < 4; ++j) {
        const int rb = (j << 4) + lr;
        const s16x8 bk = *(const s16x8*)((const char*)Kl + (rb << 7) +
                                         ((((kk << 2) + hi) ^ (rb & 7)) << 4));
        s[j] = __builtin_amdgcn_mfma_f32_16x16x32_bf16(aq[kk], bk, s[j], 0, 0, 0);
      }

    const bool diag = (kt == qt);
#pragma unroll
    for (int j = 0; j < 4; ++j) {
      f32x4 sv = s[j] * 0.125f;
      if (diag) {
        const int col = (j << 4) + lr;
#pragma unroll
        for (int rg = 0; rg < 4; ++rg) {
          const int row = (w << 4) + (hi << 2) + rg;
          if (col > row) sv[rg] = -1e30f;
        }
      }
      s[j] = sv;
    }

#pragma unroll
    for (int rg = 0; rg < 4; ++rg) {
      float mx = fmaxf(fmaxf(s[0][rg], s[1][rg]), fmaxf(s[2][rg], s[3][rg]));
      mx = fmaxf(mx, __shfl_xor(mx, 1));
      mx = fmaxf(mx, __shfl_xor(mx, 2));
      mx = fmaxf(mx, __shfl_xor(mx, 4));
      mx = fmaxf(mx, __shfl_xor(mx, 8));
      const float mn = fmaxf(m[rg], mx);
      const float sc = __expf(m[rg] - mn);
      m[rg] = mn;
      float rs = 0.f;
#pragma unroll
      for (int j = 0; j < 4; ++j) {
        const float e = __expf(s[j][rg] - mn);
        s[j][rg] = e;
        rs += e;
      }
      rs += __shfl_xor(rs, 1);
      rs += __shfl_xor(rs, 2);
      rs += __shfl_xor(rs, 4);
      rs += __shfl_xor(rs, 8);
      lsum[rg] = lsum[rg] * sc + rs;
#pragma unroll
      for (int j2 = 0; j2 < 4; ++j2) ofr[j2][rg] *= sc;
    }

#pragma unroll
    for (int j = 0; j < 4; ++j)
#pragma unroll
      for (int rg = 0; rg < 4; ++rg) {
        const int row = (hi << 2) + rg, col = (j << 4) + lr;
        Pl[w][(row << 6) + (col ^ ((row & 7) << 3))] = f2bf(s[j][rg]);
      }

#pragma unroll
    for (int kk = 0; kk < 2; ++kk) {
      const s16x8 ap = *(const s16x8*)((const char*)&Pl[w][0] + (lr << 7) +
                                       (((kk << 6) + (hi << 4)) ^ ((lr & 7) << 4)));
#pragma unroll
      for (int j2 = 0; j2 < 4; ++j2) {
        const int rb = (j2 << 4) + lr;
        const s16x8 bv = *(const s16x8*)((const char*)Vt + (rb << 7) +
                                         ((((kk << 2) + hi) ^ (rb & 7)) << 4));
        ofr[j2] = __builtin_amdgcn_mfma_f32_16x16x32_bf16(ap, bv, ofr[j2], 0, 0, 0);
      }
    }
    __syncthreads();
  }

  float rinv[4];
#pragma unroll
  for (int rg = 0; rg < 4; ++rg) rinv[rg] = 1.f / lsum[rg];
#pragma unroll
  for (int j2 = 0; j2 < 4; ++j2)
#pragma unroll
    for (int rg = 0; rg < 4; ++rg) {
      const int row = (qt << 6) + (w << 4) + (hi << 2) + rg;
      const int col = (h << 6) + (j2 << 4) + lr;
      o[(bT + row) * 1024 + col] = f2bf(ofr[j2][rg] * rinv[rg]);
    }
}

// ---------------------------------------------------------------------------
extern "C" void kernel_launch(void* const* d_in, const int* in_sizes, int n_in,
                              void* d_out, int out_size, void* d_ws, size_t ws_size,
                              hipStream_t stream) {
  (void)in_sizes; (void)n_in; (void)out_size; (void)ws_size;
  const int* idx = (const int*)d_in[0];
  const float* tokE = (const float*)d_in[1];
  const float* posE = (const float*)d_in[2];
  const float* Wq = (const float*)d_in[3];
  const float* Wk = (const float*)d_in[4];
  const float* Wv = (const float*)d_in[5];
  const float* Wp = (const float*)d_in[6];
  const float* bp = (const float*)d_in[7];
  const float* ln1g = (const float*)d_in[8];
  const float* ln1b = (const float*)d_in[9];
  const float* ln2g = (const float*)d_in[10];
  const float* ln2b = (const float*)d_in[11];
  const float* W1 = (const float*)d_in[12];
  const float* b1 = (const float*)d_in[13];
  const float* W2 = (const float*)d_in[14];
  const float* b2 = (const float*)d_in[15];
  const float* lnfg = (const float*)d_in[16];
  const float* lnfb = (const float*)d_in[17];
  const float* Wlm = (const float*)d_in[18];
  const float* blm = (const float*)d_in[19];

  char* p = (char*)d_ws;
  float* x = (float*)p;   p += (size_t)BT_ * D_ * 4;
  u16* xn = (u16*)p;      p += (size_t)BT_ * D_ * 2;
  u16* qkv = (u16*)p;     p += (size_t)BT_ * 3072 * 2;
  u16* ob = (u16*)p;      p += (size_t)BT_ * D_ * 2;
  u16* hb = (u16*)p;      p += (size_t)BT_ * FF_ * 2;
  u16* WqkvT = (u16*)p;   p += (size_t)L_ * 3072 * D_ * 2;
  u16* WpT = (u16*)p;     p += (size_t)L_ * D_ * D_ * 2;
  u16* W1T = (u16*)p;     p += (size_t)L_ * FF_ * D_ * 2;
  u16* W2T = (u16*)p;     p += (size_t)L_ * D_ * FF_ * 2;
  u16* WlmT = (u16*)p;    p += (size_t)V_ * D_ * 2;

  dim3 blk(256);
  dim3 blk512(512);
  // weight convert+transpose (bf16, [N][K]) — every call (no caching allowed)
  for (int l = 0; l < L_; ++l) {
    tconv_kernel<<<dim3(32, 32), blk, 0, stream>>>(Wq + (size_t)l * D_ * D_,
                                                   WqkvT + (size_t)l * 3072 * D_, D_, D_);
    tconv_kernel<<<dim3(32, 32), blk, 0, stream>>>(
        Wk + (size_t)l * D_ * D_, WqkvT + (size_t)l * 3072 * D_ + D_ * D_, D_, D_);
    tconv_kernel<<<dim3(32, 32), blk, 0, stream>>>(
        Wv + (size_t)l * D_ * D_, WqkvT + (size_t)l * 3072 * D_ + 2 * D_ * D_, D_, D_);
    tconv_kernel<<<dim3(32, 32), blk, 0, stream>>>(Wp + (size_t)l * D_ * D_,
                                                   WpT + (size_t)l * D_ * D_, D_, D_);
    tconv_kernel<<<dim3(128, 32), blk, 0, stream>>>(W1 + (size_t)l * D_ * FF_,
                                                    W1T + (size_t)l * FF_ * D_, D_, FF_);
    tconv_kernel<<<dim3(32, 128), blk, 0, stream>>>(W2 + (size_t)l * FF_ * D_,
                                                    W2T + (size_t)l * D_ * FF_, FF_, D_);
  }
  tconv_kernel<<<dim3(1000, 32), blk, 0, stream>>>(Wlm, WlmT, D_, V_);

  embed_kernel<<<dim3(BT_), blk, 0, stream>>>(idx, tokE, posE, x);

  for (int l = 0; l < L_; ++l) {
    ln_kernel<<<dim3(BT_), blk, 0, stream>>>(x, ln1g + l * D_, ln1b + l * D_, xn);
    gemm256<0><<<dim3(192), blk512, 0, stream>>>(xn, WqkvT + (size_t)l * 3072 * D_,
                                                 nullptr, nullptr, qkv, BT_, 3072, D_, 16);
    fattn_kernel<<<dim3(T_ / 64, H_, B_), blk, 0, stream>>>(qkv, ob);
    gemm_bt<1><<<dim3(8, 32), blk, 0, stream>>>(ob, WpT + (size_t)l * D_ * D_,
                                                bp + l * D_, x, nullptr, BT_, D_, D_);
    ln_kernel<<<dim3(BT_), blk, 0, stream>>>(x, ln2g + l * D_, ln2b + l * D_, xn);
    gemm256<2><<<dim3(256), blk512, 0, stream>>>(xn, W1T + (size_t)l * FF_ * D_,
                                                 b1 + l * FF_, nullptr, hb, BT_, FF_, D_, 16);
    gemm_bt<1><<<dim3(8, 32), blk, 0, stream>>>(hb, W2T + (size_t)l * D_ * FF_,
                                                b2 + l * D_, x, nullptr, BT_, D_, FF_);
  }
  ln_kernel<<<dim3(BT_), blk, 0, stream>>>(x, lnfg, lnfb, xn);
  gemm256<3><<<dim3(2000), blk512, 0, stream>>>(xn, WlmT, blm, (float*)d_out, nullptr,
                                                BT_, V_, D_, 16);
}

// Round 6
// 2966.746 us; speedup vs baseline: 1.0622x; 1.0273x over previous
//
#include <hip/hip_runtime.h>
#include <cstdint>

typedef __attribute__((ext_vector_type(4))) float f32x4;
typedef __attribute__((ext_vector_type(8))) short s16x8;
typedef __attribute__((ext_vector_type(4))) short s16x4;
typedef unsigned short u16;
typedef unsigned int u32;
typedef __attribute__((address_space(1))) void gas_void;
typedef __attribute__((address_space(3))) void las_void;

#define B_ 4
#define T_ 1024
#define V_ 32000
#define D_ 1024
#define H_ 16
#define HS_ 64
#define FF_ 4096
#define L_ 8
#define BT_ (B_ * T_)

__device__ __forceinline__ float bf2f(u16 h) { return __uint_as_float(((u32)h) << 16); }
__device__ __forceinline__ u16 f2bf(float f) {
  u32 u = __float_as_uint(f);
  u += 0x7fffu + ((u >> 16) & 1u);
  return (u16)(u >> 16);
}

// async global->LDS, 16B per lane; lds dest must be wave-uniform base (+lane*16 by HW)
__device__ __forceinline__ void gld16(const void* g, void* l) {
  __builtin_amdgcn_global_load_lds((gas_void*)(uintptr_t)g,
                                   (las_void*)(u32)(uintptr_t)l, 16, 0, 0);
}

// LDS 64B-row tiles: physical chunk c holds logical k-chunk l = (c - (row>>1))&3.
// Read side: c = (l + (row>>1))&3 -> per-16-lane group every (parity,chunk)
// cell is hit exactly 2x = conflict-free (2-way is free, m136).

// ---------------------------------------------------------------------------
// gemm256: C[M,N] = A[M,K] @ Bt^T.  256x256 tile, BK=64, 8 waves (2Mx4N),
// 8-phase schedule w/ counted vmcnt (T3+T4), setprio (T5), XCD swizzle (T1).
// B-fragments loaded on odd phases, reused from registers on even phases.
// Requires M%256==0, N%256==0, K%128==0, K>=256, grid%8==0.
// EPI: 0 = bf16 out; 2 = bf16 + bias + relu; 3 = f32 + bias.
// ---------------------------------------------------------------------------
template <int EPI>
__global__ __launch_bounds__(512, 2) void gemm256(
    const u16* __restrict__ A, const u16* __restrict__ Bt,
    const float* __restrict__ bias, float* Cf, u16* Cb,
    int M, int N, int K, int nrowb) {
  __shared__ u16 lds[2][2][2][8192];  // [buf][khalf][A/B][256*32] = 128 KiB
  const int tid = threadIdx.x;
  const int lane = tid & 63;
  const int lr = lane & 15, hi = lane >> 4;
  const int wid = tid >> 6;
  const int wm128 = (wid >> 2) << 7;
  const int wn64 = (wid & 3) << 6;
  const int logical = ((int)blockIdx.x & 7) * ((int)gridDim.x >> 3) + ((int)blockIdx.x >> 3);
  const int row0 = (logical % nrowb) << 8;
  const int col0 = (logical / nrowb) << 8;
  const int NT = K >> 6;
  const int srow = tid >> 2;   // staging row within 8KB shot
  const int schunk = tid & 3;  // staging dest 16B chunk
  const int xo = ((hi + (lr >> 1)) & 3) << 4;  // frag-read swizzle byte offset

  f32x4 acc[32];
#pragma unroll
  for (int i = 0; i < 32; ++i) acc[i] = f32x4{0.f, 0.f, 0.f, 0.f};
  s16x8 bfr[4];  // B fragments persist across phase pairs

#define VMW(N) asm volatile("s_waitcnt vmcnt(" #N ")" ::: "memory")

#define STG(DB, DK, OP, KT)                                                    \
  {                                                                            \
    const u16* sp_ = (OP) ? Bt : A;                                            \
    const int base_ = (OP) ? col0 : row0;                                      \
    const int c0_ = ((KT) << 6) + ((DK) << 5);                                 \
    _Pragma("unroll")                                                          \
    for (int sh_ = 0; sh_ < 2; ++sh_) {                                        \
      const int rr_ = (sh_ << 7) + srow;                                       \
      const int ko_ = ((schunk - (rr_ >> 1)) & 3) << 3;                        \
      gld16(sp_ + (size_t)(base_ + rr_) * K + c0_ + ko_,                       \
            (char*)&lds[DB][DK][OP][0] + (sh_ << 13) + (wid << 10));           \
    }                                                                          \
  }

#define PHASE(BUF, MH, KS, LOADB, STG_STMT, VM_STMT)                           \
  {                                                                            \
    __builtin_amdgcn_sched_barrier(0);                                         \
    const char* As_ = (const char*)&lds[BUF][KS][0][0];                        \
    const char* Bs_ = (const char*)&lds[BUF][KS][1][0];                        \
    const int ra_ = wm128 + ((MH) << 6) + lr;                                  \
    s16x8 af_[4];                                                              \
    _Pragma("unroll")                                                          \
    for (int q_ = 0; q_ < 4; ++q_)                                             \
      af_[q_] = *(const s16x8*)(As_ + ((ra_ + (q_ << 4)) << 6) + xo);          \
    if (LOADB) {                                                               \
      _Pragma("unroll")                                                        \
      for (int q_ = 0; q_ < 4; ++q_)                                           \
        bfr[q_] = *(const s16x8*)(Bs_ + ((wn64 + lr + (q_ << 4)) << 6) + xo);  \
    }                                                                          \
    STG_STMT;                                                                  \
    __builtin_amdgcn_sched_barrier(0);                                         \
    __builtin_amdgcn_s_barrier();                                              \
    asm volatile("s_waitcnt lgkmcnt(0)" ::: "memory");                         \
    __builtin_amdgcn_sched_barrier(0);                                         \
    __builtin_amdgcn_s_setprio(1);                                             \
    _Pragma("unroll")                                                          \
    for (int mi_ = 0; mi_ < 4; ++mi_) {                                        \
      _Pragma("unroll")                                                        \
      for (int nj_ = 0; nj_ < 4; ++nj_)                                        \
        acc[((MH)*4 + mi_) * 4 + nj_] = __builtin_amdgcn_mfma_f32_16x16x32_bf16( \
            af_[mi_], bfr[nj_], acc[((MH)*4 + mi_) * 4 + nj_], 0, 0, 0);       \
    }                                                                          \
    __builtin_amdgcn_s_setprio(0);                                             \
    __builtin_amdgcn_sched_barrier(0);                                         \
    VM_STMT;                                                                   \
    __builtin_amdgcn_s_barrier();                                              \
  }

  // prologue: 6 half-slot stages (tile0 full, tile1 k0-halves), 12 loads
  STG(0, 0, 0, 0)
  STG(0, 0, 1, 0)
  STG(0, 1, 0, 0)
  STG(0, 1, 1, 0)
  STG(1, 0, 0, 1)
  STG(1, 0, 1, 1)
  VMW(8);  // oldest 4 (buf0 ks0 A+B) complete
  __builtin_amdgcn_s_barrier();

  const int NI = NT >> 1;
  for (int it = 0; it < NI - 1; ++it) {
    const int t1 = 2 * it + 1, t2 = 2 * it + 2, t3 = 2 * it + 3;
    PHASE(0, 0, 0, 1, STG(1, 1, 0, t1), )
    PHASE(0, 1, 0, 0, STG(1, 1, 1, t1), VMW(6))
    PHASE(0, 0, 1, 1, STG(0, 0, 0, t2), )
    PHASE(0, 1, 1, 0, STG(0, 0, 1, t2), VMW(6))
    PHASE(1, 0, 0, 1, STG(0, 1, 0, t2), )
    PHASE(1, 1, 0, 0, STG(0, 1, 1, t2), VMW(6))
    PHASE(1, 0, 1, 1, STG(1, 0, 0, t3), )
    PHASE(1, 1, 1, 0, STG(1, 0, 1, t3), VMW(6))
  }
  // epilogue iteration: tiles NT-2 (buf0), NT-1 (buf1); stage only buf1 khalf1.
  {
    PHASE(0, 0, 0, 1, STG(1, 1, 0, NT - 1), )
    PHASE(0, 1, 0, 0, STG(1, 1, 1, NT - 1), VMW(8))
    PHASE(0, 0, 1, 1, (void)0, )
    PHASE(0, 1, 1, 0, (void)0, VMW(4))
    PHASE(1, 0, 0, 1, (void)0, )
    PHASE(1, 1, 0, 0, (void)0, VMW(0))
    PHASE(1, 0, 1, 1, (void)0, )
    PHASE(1, 1, 1, 0, (void)0, )
  }
#undef PHASE
#undef STG
#undef VMW

  const int gr0 = row0 + wm128;
  const int gc0 = col0 + wn64;
#pragma unroll
  for (int nj = 0; nj < 4; ++nj) {
    const int col = gc0 + (nj << 4) + lr;
    const float bv = (EPI != 0) ? bias[col] : 0.f;
#pragma unroll
    for (int mi = 0; mi < 8; ++mi) {
#pragma unroll
      for (int rg = 0; rg < 4; ++rg) {
        const int row = gr0 + (mi << 4) + (hi << 2) + rg;
        const size_t off = (size_t)row * N + col;
        float val = acc[mi * 4 + nj][rg] + bv;
        if constexpr (EPI == 2) val = fmaxf(val, 0.f);
        if constexpr (EPI == 0 || EPI == 2) Cb[off] = f2bf(val);
        else Cf[off] = val;
      }
    }
  }
}

// ---------------------------------------------------------------------------
// GEMM 128x128 (m97 structure): used for QKV / proj / FF2.
// EPI: 0 = bf16 out; 1 = f32 out + bias + residual(in-place Cf).
// ---------------------------------------------------------------------------
template <int EPI>
__global__ __launch_bounds__(256) void gemm_bt(
    const u16* __restrict__ A, const u16* __restrict__ Bt,
    const float* __restrict__ bias, float* Cf, u16* Cb,
    int M, int N, int K) {
  __shared__ u16 lds[2][2][4096];  // [buf][A/B][128*32] = 32 KiB
  const int tid = threadIdx.x;
  const int lane = tid & 63;
  const int lr = lane & 15, hi = lane >> 4;
  const int wid = tid >> 6;
  const int wm = wid >> 1, wn = wid & 1;
  const int row0 = blockIdx.y << 7, col0 = blockIdx.x << 7;
  const int NT = K >> 5;
  const int wbase = (tid & ~63) << 4;
  const int xo = ((hi + (lr >> 1)) & 3) << 4;

  f32x4 acc[4][4];
#pragma unroll
  for (int i = 0; i < 4; ++i)
#pragma unroll
    for (int j = 0; j < 4; ++j) acc[i][j] = f32x4{0.f, 0.f, 0.f, 0.f};

  auto stage = [&](int buf, int kt) {
#pragma unroll
    for (int c = 0; c < 2; ++c) {
      const int o = (c << 12) + (tid << 4);
      const int r = o >> 6;
      const int ko = ((((o >> 4) & 3) - (r >> 1)) & 3) << 3;  // logical k elems
      gld16(A + (size_t)(row0 + r) * K + (kt << 5) + ko,
            (char*)&lds[buf][0][0] + (c << 12) + wbase);
      gld16(Bt + (size_t)(col0 + r) * K + (kt << 5) + ko,
            (char*)&lds[buf][1][0] + (c << 12) + wbase);
    }
  };

  stage(0, 0);
  __syncthreads();
  int cur = 0;
  for (int kt = 0; kt < NT; ++kt) {
    if (kt + 1 < NT) stage(cur ^ 1, kt + 1);
    const char* As = (const char*)&lds[cur][0][0];
    const char* Bs = (const char*)&lds[cur][1][0];
    s16x8 af[4], bfr[4];
#pragma unroll
    for (int i = 0; i < 4; ++i) {
      const int ra = (wm << 6) + (i << 4) + lr;
      af[i] = *(const s16x8*)(As + (ra << 6) + xo);
      const int rb = (wn << 6) + (i << 4) + lr;
      bfr[i] = *(const s16x8*)(Bs + (rb << 6) + xo);
    }
#pragma unroll
    for (int i = 0; i < 4; ++i)
#pragma unroll
      for (int j = 0; j < 4; ++j)
        acc[i][j] =
            __builtin_amdgcn_mfma_f32_16x16x32_bf16(af[i], bfr[j], acc[i][j], 0, 0, 0);
    __syncthreads();
    cur ^= 1;
  }

  const int gr = row0 + (wm << 6);
  const int gc = col0 + (wn << 6);
#pragma unroll
  for (int j = 0; j < 4; ++j) {
    const int col = gc + (j << 4) + lr;
    const float bv = (EPI != 0) ? bias[col] : 0.f;
#pragma unroll
    for (int i = 0; i < 4; ++i) {
#pragma unroll
      for (int rg = 0; rg < 4; ++rg) {
        const int row = gr + (i << 4) + (hi << 2) + rg;
        const size_t off = (size_t)row * N + col;
        float val = acc[i][j][rg] + bv;
        if constexpr (EPI == 1) val += Cf[off];
        if constexpr (EPI == 2) val = fmaxf(val, 0.f);
        if constexpr (EPI == 0 || EPI == 2) Cb[off] = f2bf(val);
        else Cf[off] = val;
      }
    }
  }
}

// ---------------------------------------------------------------------------
// LayerNorm over D=1024, f32 in -> bf16 out. One block per row.
// ---------------------------------------------------------------------------
__global__ __launch_bounds__(256) void ln_kernel(const float* __restrict__ x,
                                                 const float* __restrict__ gw,
                                                 const float* __restrict__ bw,
                                                 u16* __restrict__ out) {
  const int r = blockIdx.x, tid = threadIdx.x;
  const int lane = tid & 63, wid = tid >> 6;
  __shared__ float red[8];
  f32x4 v = *(const f32x4*)(x + ((size_t)r << 10) + (tid << 2));
  float s = v[0] + v[1] + v[2] + v[3];
  float q = v[0] * v[0] + v[1] * v[1] + v[2] * v[2] + v[3] * v[3];
#pragma unroll
  for (int off = 32; off; off >>= 1) {
    s += __shfl_down(s, off);
    q += __shfl_down(q, off);
  }
  if (lane == 0) {
    red[wid] = s;
    red[4 + wid] = q;
  }
  __syncthreads();
  const float mean = (red[0] + red[1] + red[2] + red[3]) * (1.f / 1024.f);
  const float var = (red[4] + red[5] + red[6] + red[7]) * (1.f / 1024.f) - mean * mean;
  const float rstd = rsqrtf(var + 1e-5f);
  f32x4 g4 = *(const f32x4*)(gw + (tid << 2));
  f32x4 b4 = *(const f32x4*)(bw + (tid << 2));
  u16* op = out + ((size_t)r << 10) + (tid << 2);
#pragma unroll
  for (int j = 0; j < 4; ++j) op[j] = f2bf((v[j] - mean) * rstd * g4[j] + b4[j]);
}

// ---------------------------------------------------------------------------
// Embedding: x[r] = tok_emb[idx[r]] + pos_emb[r % T]
// ---------------------------------------------------------------------------
__global__ __launch_bounds__(256) void embed_kernel(const int* __restrict__ idx,
                                                    const float* __restrict__ tok,
                                                    const float* __restrict__ pos,
                                                    float* __restrict__ x) {
  const int r = blockIdx.x, tid = threadIdx.x;
  const int t = r & (T_ - 1);
  const int tk = idx[r];
  f32x4 a = *(const f32x4*)(tok + ((size_t)tk << 10) + (tid << 2));
  f32x4 p = *(const f32x4*)(pos + ((size_t)t << 10) + (tid << 2));
  *(f32x4*)(x + ((size_t)r << 10) + (tid << 2)) = a + p;
}

// ---------------------------------------------------------------------------
// Transpose + f32->bf16: src [K][N] f32 -> dst [N][K] bf16. 32x32 LDS tiles.
// ---------------------------------------------------------------------------
__global__ __launch_bounds__(256) void tconv_kernel(const float* __restrict__ src,
                                                    u16* __restrict__ dst, int K, int N) {
  __shared__ float tile[32][33];
  const int tx = threadIdx.x & 31, ty = threadIdx.x >> 5;
  const int n0 = blockIdx.x << 5, k0 = blockIdx.y << 5;
#pragma unroll
  for (int i = 0; i < 32; i += 8)
    tile[ty + i][tx] = src[(size_t)(k0 + ty + i) * N + n0 + tx];
  __syncthreads();
#pragma unroll
  for (int i = 0; i < 32; i += 8)
    dst[(size_t)(n0 + ty + i) * K + k0 + tx] = f2bf(tile[tx][ty + i]);
}

// ---------------------------------------------------------------------------
// Flash attention v2 (causal), swapped-QK^T, in-register P, dbuf K/V.
// qkv bf16 [B*T][3072] (q|k|v, each h*64+hs). Block = 4 waves, 64 q-rows.
// S^T = mfma(K, Q): lane holds S[q=lr][kv=16j+4hi+rg] -> lane-local softmax.
// PV with k-slot bijection pi(hi,s)=16(s>>2)+4hi+(s&3) applied to BOTH
// operands: P packs straight from registers; V^T read as 2x ds_read_b64.
// One raw s_barrier per tile; prefetch next K (gld16) + V (regs) before
// compute, vmcnt(0) after compute (T14), setprio around MFMA (T5).
// ---------------------------------------------------------------------------
__global__ __launch_bounds__(256) void fattn_kernel(const u16* __restrict__ qkv,
                                                    u16* __restrict__ o) {
  const int qt = blockIdx.x, h = blockIdx.y, b = blockIdx.z;
  const int tid = threadIdx.x;
  const int lane = tid & 63;
  const int lr = lane & 15, hi = lane >> 4;
  const int w = tid >> 6;
  __shared__ alignas(16) u16 Kl[2][4096];  // [buf][kv][64 d], 128B rows, XOR-swz
  __shared__ alignas(16) u16 Vt[2][4096];  // [buf][d][64 kv], 128B rows, XOR-swz

  const size_t bT = (size_t)(b * T_);
  const int q_row = (qt << 6) + (w << 4) + lr;
  const size_t qbase = (bT + q_row) * 3072 + (h << 6);
  s16x8 aq[2];
  aq[0] = *(const s16x8*)(qkv + qbase + hi * 8);
  aq[1] = *(const s16x8*)(qkv + qbase + 32 + hi * 8);

  f32x4 ofr[4];
#pragma unroll
  for (int j = 0; j < 4; ++j) ofr[j] = f32x4{0.f, 0.f, 0.f, 0.f};
  float mrun = -1e30f, lsum = 0.f;

  uint4 vr0, vr1;

#define STAGEK(BUF, KT)                                                        \
  {                                                                            \
    _Pragma("unroll")                                                          \
    for (int sh_ = 0; sh_ < 2; ++sh_) {                                        \
      const int ob_ = (sh_ << 12) + (tid << 4);                                \
      const int r_ = ob_ >> 7;                                                 \
      const int il_ = (ob_ & 127) ^ ((r_ & 7) << 4);                           \
      gld16(qkv + (bT + ((KT) << 6) + r_) * 3072 + 1024 + (h << 6) + (il_ >> 1), \
            (char*)&Kl[BUF][0] + (sh_ << 12) + ((tid & 192) << 4));            \
    }                                                                          \
  }
#define LOADV(KT)                                                              \
  {                                                                            \
    const u16* vs_ =                                                           \
        qkv + (bT + ((KT) << 6) + lane) * 3072 + 2048 + (h << 6) + (w << 4);   \
    vr0 = *(const uint4*)vs_;                                                  \
    vr1 = *(const uint4*)(vs_ + 8);                                            \
  }
#define WRITEV(BUF)                                                            \
  {                                                                            \
    const u16* p0_ = (const u16*)&vr0;                                         \
    const u16* p1_ = (const u16*)&vr1;                                         \
    _Pragma("unroll")                                                          \
    for (int j_ = 0; j_ < 8; ++j_) {                                           \
      const int sw_ = lane ^ (j_ << 3);                                        \
      Vt[BUF][(((w << 4) + j_) << 6) + sw_] = p0_[j_];                         \
      Vt[BUF][(((w << 4) + 8 + j_) << 6) + sw_] = p1_[j_];                     \
    }                                                                          \
  }

  STAGEK(0, 0)
  LOADV(0)
  asm volatile("s_waitcnt vmcnt(0)" ::: "memory");
  WRITEV(0)
  asm volatile("s_waitcnt lgkmcnt(0)" ::: "memory");
  __builtin_amdgcn_sched_barrier(0);
  __builtin_amdgcn_s_barrier();

  int cur = 0;
  for (int kt = 0; kt <= qt; ++kt) {
    if (kt < qt) {
      STAGEK(cur ^ 1, kt + 1)
      LOADV(kt + 1)
    }

    // --- S^T = K Q^T : lane holds S[q=lr][kv = 16j + 4hi + rg] ---
    f32x4 s[4];
#pragma unroll
    for (int j = 0; j < 4; ++j) s[j] = f32x4{0.f, 0.f, 0.f, 0.f};
    __builtin_amdgcn_s_setprio(1);
#pragma unroll
    for (int kk = 0; kk < 2; ++kk)
#pragma unroll
      for (int j = 0; j < 4; ++j) {
        const int rb = (j << 4) + lr;
        const s16x8 bk = *(const s16x8*)((const char*)&Kl[cur][0] + (rb << 7) +
                                         ((((kk << 2) + hi) ^ (rb & 7)) << 4));
        s[j] = __builtin_amdgcn_mfma_f32_16x16x32_bf16(bk, aq[kk], s[j], 0, 0, 0);
      }
    __builtin_amdgcn_s_setprio(0);

    // --- scale + causal mask (diagonal tile only) ---
    if (kt == qt) {
      const int qr = (w << 4) + lr;
#pragma unroll
      for (int j = 0; j < 4; ++j)
#pragma unroll
        for (int rg = 0; rg < 4; ++rg) {
          const int kvr = (j << 4) + (hi << 2) + rg;
          s[j][rg] = (kvr > qr) ? -1e30f : s[j][rg] * 0.125f;
        }
    } else {
#pragma unroll
      for (int j = 0; j < 4; ++j) s[j] = s[j] * 0.125f;
    }

    // --- online softmax, q = lr lane-local; reduce across hi via shfl ---
    float mx = -1e30f;
#pragma unroll
    for (int j = 0; j < 4; ++j)
#pragma unroll
      for (int rg = 0; rg < 4; ++rg) mx = fmaxf(mx, s[j][rg]);
    mx = fmaxf(mx, __shfl_xor(mx, 16));
    mx = fmaxf(mx, __shfl_xor(mx, 32));
    const float mn = fmaxf(mrun, mx);
    const float sc = __expf(mrun - mn);
    mrun = mn;
    float rs = 0.f;
#pragma unroll
    for (int j = 0; j < 4; ++j)
#pragma unroll
      for (int rg = 0; rg < 4; ++rg) {
        const float e = __expf(s[j][rg] - mn);
        s[j][rg] = e;
        rs += e;
      }
    rs += __shfl_xor(rs, 16);
    rs += __shfl_xor(rs, 32);
    lsum = lsum * sc + rs;
    float scO[4];
#pragma unroll
    for (int rg = 0; rg < 4; ++rg) scO[rg] = __shfl(sc, (hi << 2) + rg);
#pragma unroll
    for (int j2 = 0; j2 < 4; ++j2)
#pragma unroll
      for (int rg = 0; rg < 4; ++rg) ofr[j2][rg] *= scO[rg];

    // --- pack P (A-frag, pi-mapped): slot s <- s[2kk+(s>>2)][s&3] ---
    s16x8 pb[2];
#pragma unroll
    for (int kk = 0; kk < 2; ++kk)
#pragma unroll
      for (int i = 0; i < 4; ++i) {
        pb[kk][i] = (short)f2bf(s[2 * kk][i]);
        pb[kk][4 + i] = (short)f2bf(s[2 * kk + 1][i]);
      }

    // --- O += P V (V^T b64 reads, pi-mapped) ---
    __builtin_amdgcn_s_setprio(1);
#pragma unroll
    for (int kk = 0; kk < 2; ++kk)
#pragma unroll
      for (int j2 = 0; j2 < 4; ++j2) {
        const int drow = (j2 << 4) + lr;
        const int swz = (drow & 7) << 3;
        const int base = drow << 6;
        const s16x4 lo = *(const s16x4*)&Vt[cur][base + (((kk << 5) + (hi << 2)) ^ swz)];
        const s16x4 hv = *(const s16x4*)&Vt[cur][base + (((kk << 5) + 16 + (hi << 2)) ^ swz)];
        const s16x8 vb = __builtin_shufflevector(lo, hv, 0, 1, 2, 3, 4, 5, 6, 7);
        ofr[j2] = __builtin_amdgcn_mfma_f32_16x16x32_bf16(pb[kk], vb, ofr[j2], 0, 0, 0);
      }
    __builtin_amdgcn_s_setprio(0);

    if (kt < qt) {
      asm volatile("s_waitcnt vmcnt(0)" ::: "memory");
      WRITEV(cur ^ 1)
    }
    asm volatile("s_waitcnt lgkmcnt(0)" ::: "memory");
    __builtin_amdgcn_sched_barrier(0);
    __builtin_amdgcn_s_barrier();
    cur ^= 1;
  }

  // --- epilogue: lane holds O[q = hi*4+rg][d = j2*16+lr] ---
  const float rinv = 1.f / lsum;
  float rO[4];
#pragma unroll
  for (int rg = 0; rg < 4; ++rg) rO[rg] = __shfl(rinv, (hi << 2) + rg);
#pragma unroll
  for (int j2 = 0; j2 < 4; ++j2)
#pragma unroll
    for (int rg = 0; rg < 4; ++rg) {
      const int row = (qt << 6) + (w << 4) + (hi << 2) + rg;
      const int col = (h << 6) + (j2 << 4) + lr;
      o[(bT + row) * 1024 + col] = f2bf(ofr[j2][rg] * rO[rg]);
    }
#undef STAGEK
#undef LOADV
#undef WRITEV
}

// ---------------------------------------------------------------------------
extern "C" void kernel_launch(void* const* d_in, const int* in_sizes, int n_in,
                              void* d_out, int out_size, void* d_ws, size_t ws_size,
                              hipStream_t stream) {
  (void)in_sizes; (void)n_in; (void)out_size; (void)ws_size;
  const int* idx = (const int*)d_in[0];
  const float* tokE = (const float*)d_in[1];
  const float* posE = (const float*)d_in[2];
  const float* Wq = (const float*)d_in[3];
  const float* Wk = (const float*)d_in[4];
  const float* Wv = (const float*)d_in[5];
  const float* Wp = (const float*)d_in[6];
  const float* bp = (const float*)d_in[7];
  const float* ln1g = (const float*)d_in[8];
  const float* ln1b = (const float*)d_in[9];
  const float* ln2g = (const float*)d_in[10];
  const float* ln2b = (const float*)d_in[11];
  const float* W1 = (const float*)d_in[12];
  const float* b1 = (const float*)d_in[13];
  const float* W2 = (const float*)d_in[14];
  const float* b2 = (const float*)d_in[15];
  const float* lnfg = (const float*)d_in[16];
  const float* lnfb = (const float*)d_in[17];
  const float* Wlm = (const float*)d_in[18];
  const float* blm = (const float*)d_in[19];

  char* p = (char*)d_ws;
  float* x = (float*)p;   p += (size_t)BT_ * D_ * 4;
  u16* xn = (u16*)p;      p += (size_t)BT_ * D_ * 2;
  u16* qkv = (u16*)p;     p += (size_t)BT_ * 3072 * 2;
  u16* ob = (u16*)p;      p += (size_t)BT_ * D_ * 2;
  u16* hb = (u16*)p;      p += (size_t)BT_ * FF_ * 2;
  u16* WqkvT = (u16*)p;   p += (size_t)L_ * 3072 * D_ * 2;
  u16* WpT = (u16*)p;     p += (size_t)L_ * D_ * D_ * 2;
  u16* W1T = (u16*)p;     p += (size_t)L_ * FF_ * D_ * 2;
  u16* W2T = (u16*)p;     p += (size_t)L_ * D_ * FF_ * 2;
  u16* WlmT = (u16*)p;    p += (size_t)V_ * D_ * 2;

  dim3 blk(256);
  dim3 blk512(512);
  // weight convert+transpose (bf16, [N][K]) — every call (no caching allowed)
  for (int l = 0; l < L_; ++l) {
    tconv_kernel<<<dim3(32, 32), blk, 0, stream>>>(Wq + (size_t)l * D_ * D_,
                                                   WqkvT + (size_t)l * 3072 * D_, D_, D_);
    tconv_kernel<<<dim3(32, 32), blk, 0, stream>>>(
        Wk + (size_t)l * D_ * D_, WqkvT + (size_t)l * 3072 * D_ + D_ * D_, D_, D_);
    tconv_kernel<<<dim3(32, 32), blk, 0, stream>>>(
        Wv + (size_t)l * D_ * D_, WqkvT + (size_t)l * 3072 * D_ + 2 * D_ * D_, D_, D_);
    tconv_kernel<<<dim3(32, 32), blk, 0, stream>>>(Wp + (size_t)l * D_ * D_,
                                                   WpT + (size_t)l * D_ * D_, D_, D_);
    tconv_kernel<<<dim3(128, 32), blk, 0, stream>>>(W1 + (size_t)l * D_ * FF_,
                                                    W1T + (size_t)l * FF_ * D_, D_, FF_);
    tconv_kernel<<<dim3(32, 128), blk, 0, stream>>>(W2 + (size_t)l * FF_ * D_,
                                                    W2T + (size_t)l * D_ * FF_, FF_, D_);
  }
  tconv_kernel<<<dim3(1000, 32), blk, 0, stream>>>(Wlm, WlmT, D_, V_);

  embed_kernel<<<dim3(BT_), blk, 0, stream>>>(idx, tokE, posE, x);

  for (int l = 0; l < L_; ++l) {
    ln_kernel<<<dim3(BT_), blk, 0, stream>>>(x, ln1g + l * D_, ln1b + l * D_, xn);
    gemm_bt<0><<<dim3(24, 32), blk, 0, stream>>>(xn, WqkvT + (size_t)l * 3072 * D_,
                                                 nullptr, nullptr, qkv, BT_, 3072, D_);
    fattn_kernel<<<dim3(T_ / 64, H_, B_), blk, 0, stream>>>(qkv, ob);
    gemm_bt<1><<<dim3(8, 32), blk, 0, stream>>>(ob, WpT + (size_t)l * D_ * D_,
                                                bp + l * D_, x, nullptr, BT_, D_, D_);
    ln_kernel<<<dim3(BT_), blk, 0, stream>>>(x, ln2g + l * D_, ln2b + l * D_, xn);
    gemm256<2><<<dim3(256), blk512, 0, stream>>>(xn, W1T + (size_t)l * FF_ * D_,
                                                 b1 + l * FF_, nullptr, hb, BT_, FF_, D_, 16);
    gemm_bt<1><<<dim3(8, 32), blk, 0, stream>>>(hb, W2T + (size_t)l * D_ * FF_,
                                                b2 + l * D_, x, nullptr, BT_, D_, FF_);
  }
  ln_kernel<<<dim3(BT_), blk, 0, stream>>>(x, lnfg, lnfb, xn);
  gemm256<3><<<dim3(2000), blk512, 0, stream>>>(xn, WlmT, blm, (float*)d_out, nullptr,
                                                BT_, V_, D_, 16);
}

// Round 7
// 2707.024 us; speedup vs baseline: 1.1641x; 1.0959x over previous
//
#include <hip/hip_runtime.h>
#include <cstdint>

typedef __attribute__((ext_vector_type(4))) float f32x4;
typedef __attribute__((ext_vector_type(8))) short s16x8;
typedef __attribute__((ext_vector_type(4))) short s16x4;
typedef unsigned short u16;
typedef unsigned int u32;
typedef __attribute__((address_space(1))) void gas_void;
typedef __attribute__((address_space(3))) void las_void;

#define B_ 4
#define T_ 1024
#define V_ 32000
#define D_ 1024
#define H_ 16
#define HS_ 64
#define FF_ 4096
#define L_ 8
#define BT_ (B_ * T_)

__device__ __forceinline__ float bf2f(u16 h) { return __uint_as_float(((u32)h) << 16); }
__device__ __forceinline__ u16 f2bf(float f) {
  u32 u = __float_as_uint(f);
  u += 0x7fffu + ((u >> 16) & 1u);
  return (u16)(u >> 16);
}

// async global->LDS, 16B per lane; lds dest must be wave-uniform base (+lane*16 by HW)
__device__ __forceinline__ void gld16(const void* g, void* l) {
  __builtin_amdgcn_global_load_lds((gas_void*)(uintptr_t)g,
                                   (las_void*)(u32)(uintptr_t)l, 16, 0, 0);
}

// LDS 64B-row tiles: physical chunk c holds logical k-chunk l = (c - (row>>1))&3.
// Read side: c = (l + (row>>1))&3 -> per-16-lane group every (parity,chunk)
// cell is hit exactly 2x = conflict-free (2-way is free, m136).

// ---------------------------------------------------------------------------
// gemm256: C[M,N] = A[M,K] @ Bt^T.  256x256 tile, BK=64, 8 waves (2Mx4N),
// 8-phase schedule w/ counted vmcnt (T3+T4), setprio (T5), XCD swizzle (T1).
// B-fragments loaded on odd phases, reused from registers on even phases.
// NOTE: VMW(6) at every even phase is REQUIRED — FIFO audit shows ph4/ph8-only
// leaves prev-PH6's B staging unfinished when PH3 reads it.
// EPI: 0 = bf16 out; 2 = bf16 + bias + relu; 3 = f32 + bias.
// ---------------------------------------------------------------------------
template <int EPI>
__global__ __launch_bounds__(512, 2) void gemm256(
    const u16* __restrict__ A, const u16* __restrict__ Bt,
    const float* __restrict__ bias, float* Cf, u16* Cb,
    int M, int N, int K, int nrowb) {
  __shared__ u16 lds[2][2][2][8192];  // [buf][khalf][A/B][256*32] = 128 KiB
  const int tid = threadIdx.x;
  const int lane = tid & 63;
  const int lr = lane & 15, hi = lane >> 4;
  const int wid = tid >> 6;
  const int wm128 = (wid >> 2) << 7;
  const int wn64 = (wid & 3) << 6;
  const int logical = ((int)blockIdx.x & 7) * ((int)gridDim.x >> 3) + ((int)blockIdx.x >> 3);
  const int row0 = (logical % nrowb) << 8;
  const int col0 = (logical / nrowb) << 8;
  const int NT = K >> 6;
  const int srow = tid >> 2;   // staging row within 8KB shot
  const int schunk = tid & 3;  // staging dest 16B chunk
  const int xo = ((hi + (lr >> 1)) & 3) << 4;  // frag-read swizzle byte offset

  f32x4 acc[32];
#pragma unroll
  for (int i = 0; i < 32; ++i) acc[i] = f32x4{0.f, 0.f, 0.f, 0.f};
  s16x8 bfr[4];  // B fragments persist across phase pairs

#define VMW(N) asm volatile("s_waitcnt vmcnt(" #N ")" ::: "memory")

#define STG(DB, DK, OP, KT)                                                    \
  {                                                                            \
    const u16* sp_ = (OP) ? Bt : A;                                            \
    const int base_ = (OP) ? col0 : row0;                                      \
    const int c0_ = ((KT) << 6) + ((DK) << 5);                                 \
    _Pragma("unroll")                                                          \
    for (int sh_ = 0; sh_ < 2; ++sh_) {                                        \
      const int rr_ = (sh_ << 7) + srow;                                       \
      const int ko_ = ((schunk - (rr_ >> 1)) & 3) << 3;                        \
      gld16(sp_ + (size_t)(base_ + rr_) * K + c0_ + ko_,                       \
            (char*)&lds[DB][DK][OP][0] + (sh_ << 13) + (wid << 10));           \
    }                                                                          \
  }

#define PHASE(BUF, MH, KS, LOADB, STG_STMT, VM_STMT)                           \
  {                                                                            \
    __builtin_amdgcn_sched_barrier(0);                                         \
    const char* As_ = (const char*)&lds[BUF][KS][0][0];                        \
    const char* Bs_ = (const char*)&lds[BUF][KS][1][0];                        \
    const int ra_ = wm128 + ((MH) << 6) + lr;                                  \
    s16x8 af_[4];                                                              \
    _Pragma("unroll")                                                          \
    for (int q_ = 0; q_ < 4; ++q_)                                             \
      af_[q_] = *(const s16x8*)(As_ + ((ra_ + (q_ << 4)) << 6) + xo);          \
    if (LOADB) {                                                               \
      _Pragma("unroll")                                                        \
      for (int q_ = 0; q_ < 4; ++q_)                                           \
        bfr[q_] = *(const s16x8*)(Bs_ + ((wn64 + lr + (q_ << 4)) << 6) + xo);  \
    }                                                                          \
    STG_STMT;                                                                  \
    __builtin_amdgcn_sched_barrier(0);                                         \
    __builtin_amdgcn_s_barrier();                                              \
    asm volatile("s_waitcnt lgkmcnt(0)" ::: "memory");                         \
    __builtin_amdgcn_sched_barrier(0);                                         \
    __builtin_amdgcn_s_setprio(1);                                             \
    _Pragma("unroll")                                                          \
    for (int mi_ = 0; mi_ < 4; ++mi_) {                                        \
      _Pragma("unroll")                                                        \
      for (int nj_ = 0; nj_ < 4; ++nj_)                                        \
        acc[((MH)*4 + mi_) * 4 + nj_] = __builtin_amdgcn_mfma_f32_16x16x32_bf16( \
            af_[mi_], bfr[nj_], acc[((MH)*4 + mi_) * 4 + nj_], 0, 0, 0);       \
    }                                                                          \
    __builtin_amdgcn_s_setprio(0);                                             \
    __builtin_amdgcn_sched_barrier(0);                                         \
    VM_STMT;                                                                   \
    __builtin_amdgcn_s_barrier();                                              \
  }

  // prologue: 6 half-slot stages (tile0 full, tile1 k0-halves), 12 loads
  STG(0, 0, 0, 0)
  STG(0, 0, 1, 0)
  STG(0, 1, 0, 0)
  STG(0, 1, 1, 0)
  STG(1, 0, 0, 1)
  STG(1, 0, 1, 1)
  VMW(8);  // oldest 4 (buf0 ks0 A+B) complete
  __builtin_amdgcn_s_barrier();

  const int NI = NT >> 1;
  for (int it = 0; it < NI - 1; ++it) {
    const int t1 = 2 * it + 1, t2 = 2 * it + 2, t3 = 2 * it + 3;
    PHASE(0, 0, 0, 1, STG(1, 1, 0, t1), )
    PHASE(0, 1, 0, 0, STG(1, 1, 1, t1), VMW(6))
    PHASE(0, 0, 1, 1, STG(0, 0, 0, t2), )
    PHASE(0, 1, 1, 0, STG(0, 0, 1, t2), VMW(6))
    PHASE(1, 0, 0, 1, STG(0, 1, 0, t2), )
    PHASE(1, 1, 0, 0, STG(0, 1, 1, t2), VMW(6))
    PHASE(1, 0, 1, 1, STG(1, 0, 0, t3), )
    PHASE(1, 1, 1, 0, STG(1, 0, 1, t3), VMW(6))
  }
  // epilogue iteration: tiles NT-2 (buf0), NT-1 (buf1); stage only buf1 khalf1.
  {
    PHASE(0, 0, 0, 1, STG(1, 1, 0, NT - 1), )
    PHASE(0, 1, 0, 0, STG(1, 1, 1, NT - 1), VMW(8))
    PHASE(0, 0, 1, 1, (void)0, )
    PHASE(0, 1, 1, 0, (void)0, VMW(4))
    PHASE(1, 0, 0, 1, (void)0, )
    PHASE(1, 1, 0, 0, (void)0, VMW(0))
    PHASE(1, 0, 1, 1, (void)0, )
    PHASE(1, 1, 1, 0, (void)0, )
  }
#undef PHASE
#undef STG
#undef VMW

  const int gr0 = row0 + wm128;
  const int gc0 = col0 + wn64;
#pragma unroll
  for (int nj = 0; nj < 4; ++nj) {
    const int col = gc0 + (nj << 4) + lr;
    const float bv = (EPI != 0) ? bias[col] : 0.f;
#pragma unroll
    for (int mi = 0; mi < 8; ++mi) {
#pragma unroll
      for (int rg = 0; rg < 4; ++rg) {
        const int row = gr0 + (mi << 4) + (hi << 2) + rg;
        const size_t off = (size_t)row * N + col;
        float val = acc[mi * 4 + nj][rg] + bv;
        if constexpr (EPI == 2) val = fmaxf(val, 0.f);
        if constexpr (EPI == 0 || EPI == 2) Cb[off] = f2bf(val);
        else Cf[off] = val;
      }
    }
  }
}

// ---------------------------------------------------------------------------
// GEMM 128x128 (m97 structure): used for QKV / proj / FF2.
// EPI: 0 = bf16 out; 1 = f32 out + bias + residual(in-place Cf).
// ---------------------------------------------------------------------------
template <int EPI>
__global__ __launch_bounds__(256) void gemm_bt(
    const u16* __restrict__ A, const u16* __restrict__ Bt,
    const float* __restrict__ bias, float* Cf, u16* Cb,
    int M, int N, int K) {
  __shared__ u16 lds[2][2][4096];  // [buf][A/B][128*32] = 32 KiB
  const int tid = threadIdx.x;
  const int lane = tid & 63;
  const int lr = lane & 15, hi = lane >> 4;
  const int wid = tid >> 6;
  const int wm = wid >> 1, wn = wid & 1;
  const int row0 = blockIdx.y << 7, col0 = blockIdx.x << 7;
  const int NT = K >> 5;
  const int wbase = (tid & ~63) << 4;
  const int xo = ((hi + (lr >> 1)) & 3) << 4;

  f32x4 acc[4][4];
#pragma unroll
  for (int i = 0; i < 4; ++i)
#pragma unroll
    for (int j = 0; j < 4; ++j) acc[i][j] = f32x4{0.f, 0.f, 0.f, 0.f};

  auto stage = [&](int buf, int kt) {
#pragma unroll
    for (int c = 0; c < 2; ++c) {
      const int o = (c << 12) + (tid << 4);
      const int r = o >> 6;
      const int ko = ((((o >> 4) & 3) - (r >> 1)) & 3) << 3;  // logical k elems
      gld16(A + (size_t)(row0 + r) * K + (kt << 5) + ko,
            (char*)&lds[buf][0][0] + (c << 12) + wbase);
      gld16(Bt + (size_t)(col0 + r) * K + (kt << 5) + ko,
            (char*)&lds[buf][1][0] + (c << 12) + wbase);
    }
  };

  stage(0, 0);
  __syncthreads();
  int cur = 0;
  for (int kt = 0; kt < NT; ++kt) {
    if (kt + 1 < NT) stage(cur ^ 1, kt + 1);
    const char* As = (const char*)&lds[cur][0][0];
    const char* Bs = (const char*)&lds[cur][1][0];
    s16x8 af[4], bfr[4];
#pragma unroll
    for (int i = 0; i < 4; ++i) {
      const int ra = (wm << 6) + (i << 4) + lr;
      af[i] = *(const s16x8*)(As + (ra << 6) + xo);
      const int rb = (wn << 6) + (i << 4) + lr;
      bfr[i] = *(const s16x8*)(Bs + (rb << 6) + xo);
    }
#pragma unroll
    for (int i = 0; i < 4; ++i)
#pragma unroll
      for (int j = 0; j < 4; ++j)
        acc[i][j] =
            __builtin_amdgcn_mfma_f32_16x16x32_bf16(af[i], bfr[j], acc[i][j], 0, 0, 0);
    __syncthreads();
    cur ^= 1;
  }

  const int gr = row0 + (wm << 6);
  const int gc = col0 + (wn << 6);
#pragma unroll
  for (int j = 0; j < 4; ++j) {
    const int col = gc + (j << 4) + lr;
    const float bv = (EPI != 0) ? bias[col] : 0.f;
#pragma unroll
    for (int i = 0; i < 4; ++i) {
#pragma unroll
      for (int rg = 0; rg < 4; ++rg) {
        const int row = gr + (i << 4) + (hi << 2) + rg;
        const size_t off = (size_t)row * N + col;
        float val = acc[i][j][rg] + bv;
        if constexpr (EPI == 1) val += Cf[off];
        if constexpr (EPI == 2) val = fmaxf(val, 0.f);
        if constexpr (EPI == 0 || EPI == 2) Cb[off] = f2bf(val);
        else Cf[off] = val;
      }
    }
  }
}

// ---------------------------------------------------------------------------
// LayerNorm over D=1024, f32 in -> bf16 out. Wave-per-row (no LDS/barrier),
// 4 rows per 256-thread block, shfl-only reduction, 8B vector stores.
// ---------------------------------------------------------------------------
__global__ __launch_bounds__(256) void ln_kernel(const float* __restrict__ x,
                                                 const float* __restrict__ gw,
                                                 const float* __restrict__ bw,
                                                 u16* __restrict__ out) {
  const int lane = threadIdx.x & 63;
  const size_t r = ((size_t)blockIdx.x << 2) + (threadIdx.x >> 6);
  const float* xp = x + (r << 10);
  f32x4 v[4];
  float s = 0.f, q = 0.f;
#pragma unroll
  for (int j = 0; j < 4; ++j) {
    v[j] = *(const f32x4*)(xp + (lane << 2) + (j << 8));
#pragma unroll
    for (int e = 0; e < 4; ++e) {
      s += v[j][e];
      q += v[j][e] * v[j][e];
    }
  }
#pragma unroll
  for (int off = 32; off; off >>= 1) {
    s += __shfl_xor(s, off);
    q += __shfl_xor(q, off);
  }
  const float mean = s * (1.f / 1024.f);
  const float var = q * (1.f / 1024.f) - mean * mean;
  const float rstd = rsqrtf(var + 1e-5f);
  u16* op = out + (r << 10);
#pragma unroll
  for (int j = 0; j < 4; ++j) {
    const f32x4 g4 = *(const f32x4*)(gw + (lane << 2) + (j << 8));
    const f32x4 b4 = *(const f32x4*)(bw + (lane << 2) + (j << 8));
    s16x4 o4;
#pragma unroll
    for (int e = 0; e < 4; ++e)
      o4[e] = (short)f2bf((v[j][e] - mean) * rstd * g4[e] + b4[e]);
    *(s16x4*)(op + (lane << 2) + (j << 8)) = o4;
  }
}

// ---------------------------------------------------------------------------
// Embedding: x[r] = tok_emb[idx[r]] + pos_emb[r % T]
// ---------------------------------------------------------------------------
__global__ __launch_bounds__(256) void embed_kernel(const int* __restrict__ idx,
                                                    const float* __restrict__ tok,
                                                    const float* __restrict__ pos,
                                                    float* __restrict__ x) {
  const int r = blockIdx.x, tid = threadIdx.x;
  const int t = r & (T_ - 1);
  const int tk = idx[r];
  f32x4 a = *(const f32x4*)(tok + ((size_t)tk << 10) + (tid << 2));
  f32x4 p = *(const f32x4*)(pos + ((size_t)t << 10) + (tid << 2));
  *(f32x4*)(x + ((size_t)r << 10) + (tid << 2)) = a + p;
}

// ---------------------------------------------------------------------------
// Transpose + f32->bf16 body: src [K][N] f32 -> dst [N][K] bf16. 32x32 tiles.
// ---------------------------------------------------------------------------
#define TCONV_BODY(SRC, DST, KK, NN)                                           \
  {                                                                            \
    __shared__ float tile[32][33];                                             \
    const int tx = threadIdx.x & 31, ty = threadIdx.x >> 5;                    \
    const int n0 = blockIdx.x << 5, k0 = blockIdx.y << 5;                      \
    _Pragma("unroll")                                                          \
    for (int i = 0; i < 32; i += 8)                                            \
      tile[ty + i][tx] = (SRC)[(size_t)(k0 + ty + i) * (NN) + n0 + tx];        \
    __syncthreads();                                                           \
    _Pragma("unroll")                                                          \
    for (int i = 0; i < 32; i += 8)                                            \
      (DST)[(size_t)(n0 + ty + i) * (KK) + k0 + tx] = f2bf(tile[tx][ty + i]);  \
  }

// All layers' Wq/Wk/Wv/Wp in one launch: grid(32, 32, 32); z = l*4 + m.
__global__ __launch_bounds__(256) void tconv_qkvp(
    const float* __restrict__ Wq, const float* __restrict__ Wk,
    const float* __restrict__ Wv, const float* __restrict__ Wp,
    u16* __restrict__ WqkvT, u16* __restrict__ WpT) {
  const int z = blockIdx.z;
  const int l = z >> 2, m = z & 3;
  const float* src;
  u16* dst;
  if (m == 0) { src = Wq + (size_t)l * D_ * D_; dst = WqkvT + (size_t)l * 3072 * D_; }
  else if (m == 1) { src = Wk + (size_t)l * D_ * D_; dst = WqkvT + (size_t)l * 3072 * D_ + D_ * D_; }
  else if (m == 2) { src = Wv + (size_t)l * D_ * D_; dst = WqkvT + (size_t)l * 3072 * D_ + 2 * D_ * D_; }
  else { src = Wp + (size_t)l * D_ * D_; dst = WpT + (size_t)l * D_ * D_; }
  TCONV_BODY(src, dst, D_, D_)
}

// All layers' W1: grid(128, 32, 8)
__global__ __launch_bounds__(256) void tconv_w1(const float* __restrict__ W1,
                                                u16* __restrict__ W1T) {
  const int l = blockIdx.z;
  TCONV_BODY(W1 + (size_t)l * D_ * FF_, W1T + (size_t)l * FF_ * D_, D_, FF_)
}

// All layers' W2: grid(32, 128, 8)
__global__ __launch_bounds__(256) void tconv_w2(const float* __restrict__ W2,
                                                u16* __restrict__ W2T) {
  const int l = blockIdx.z;
  TCONV_BODY(W2 + (size_t)l * FF_ * D_, W2T + (size_t)l * D_ * FF_, FF_, D_)
}

// Wlm: grid(1000, 32)
__global__ __launch_bounds__(256) void tconv_kernel(const float* __restrict__ src,
                                                    u16* __restrict__ dst, int K, int N) {
  TCONV_BODY(src, dst, K, N)
}

// ---------------------------------------------------------------------------
// Flash attention v2 (causal), swapped-QK^T, in-register P, dbuf K/V,
// XCD-aware (b,h) grouping: 8 (b,h) pairs per XCD -> K/V L2-resident (T1).
// ---------------------------------------------------------------------------
__global__ __launch_bounds__(256) void fattn_kernel(const u16* __restrict__ qkv,
                                                    u16* __restrict__ o) {
  const int flat = (int)blockIdx.x + ((int)blockIdx.y << 4) + ((int)blockIdx.z << 8);
  const int xcd = flat & 7, seq = flat >> 3;
  const int pair = (xcd << 3) + (seq >> 4);
  const int qt = seq & 15;
  const int h = pair & 15, b = pair >> 4;
  const int tid = threadIdx.x;
  const int lane = tid & 63;
  const int lr = lane & 15, hi = lane >> 4;
  const int w = tid >> 6;
  __shared__ alignas(16) u16 Kl[2][4096];  // [buf][kv][64 d], 128B rows, XOR-swz
  __shared__ alignas(16) u16 Vt[2][4096];  // [buf][d][64 kv], 128B rows, XOR-swz

  const size_t bT = (size_t)(b * T_);
  const int q_row = (qt << 6) + (w << 4) + lr;
  const size_t qbase = (bT + q_row) * 3072 + (h << 6);
  s16x8 aq[2];
  aq[0] = *(const s16x8*)(qkv + qbase + hi * 8);
  aq[1] = *(const s16x8*)(qkv + qbase + 32 + hi * 8);

  f32x4 ofr[4];
#pragma unroll
  for (int j = 0; j < 4; ++j) ofr[j] = f32x4{0.f, 0.f, 0.f, 0.f};
  float mrun = -1e30f, lsum = 0.f;

  uint4 vr0, vr1;

#define STAGEK(BUF, KT)                                                        \
  {                                                                            \
    _Pragma("unroll")                                                          \
    for (int sh_ = 0; sh_ < 2; ++sh_) {                                        \
      const int ob_ = (sh_ << 12) + (tid << 4);                                \
      const int r_ = ob_ >> 7;                                                 \
      const int il_ = (ob_ & 127) ^ ((r_ & 7) << 4);                           \
      gld16(qkv + (bT + ((KT) << 6) + r_) * 3072 + 1024 + (h << 6) + (il_ >> 1), \
            (char*)&Kl[BUF][0] + (sh_ << 12) + ((tid & 192) << 4));            \
    }                                                                          \
  }
#define LOADV(KT)                                                              \
  {                                                                            \
    const u16* vs_ =                                                           \
        qkv + (bT + ((KT) << 6) + lane) * 3072 + 2048 + (h << 6) + (w << 4);   \
    vr0 = *(const uint4*)vs_;                                                  \
    vr1 = *(const uint4*)(vs_ + 8);                                            \
  }
#define WRITEV(BUF)                                                            \
  {                                                                            \
    const u16* p0_ = (const u16*)&vr0;                                         \
    const u16* p1_ = (const u16*)&vr1;                                         \
    _Pragma("unroll")                                                          \
    for (int j_ = 0; j_ < 8; ++j_) {                                           \
      const int sw_ = lane ^ (j_ << 3);                                        \
      Vt[BUF][(((w << 4) + j_) << 6) + sw_] = p0_[j_];                         \
      Vt[BUF][(((w << 4) + 8 + j_) << 6) + sw_] = p1_[j_];                     \
    }                                                                          \
  }

  STAGEK(0, 0)
  LOADV(0)
  asm volatile("s_waitcnt vmcnt(0)" ::: "memory");
  WRITEV(0)
  asm volatile("s_waitcnt lgkmcnt(0)" ::: "memory");
  __builtin_amdgcn_sched_barrier(0);
  __builtin_amdgcn_s_barrier();

  int cur = 0;
  for (int kt = 0; kt <= qt; ++kt) {
    if (kt < qt) {
      STAGEK(cur ^ 1, kt + 1)
      LOADV(kt + 1)
    }

    // --- S^T = K Q^T : lane holds S[q=lr][kv = 16j + 4hi + rg] ---
    f32x4 s[4];
#pragma unroll
    for (int j = 0; j < 4; ++j) s[j] = f32x4{0.f, 0.f, 0.f, 0.f};
    __builtin_amdgcn_s_setprio(1);
#pragma unroll
    for (int kk = 0; kk < 2; ++kk)
#pragma unroll
      for (int j = 0; j < 4; ++j) {
        const int rb = (j << 4) + lr;
        const s16x8 bk = *(const s16x8*)((const char*)&Kl[cur][0] + (rb << 7) +
                                         ((((kk << 2) + hi) ^ (rb & 7)) << 4));
        s[j] = __builtin_amdgcn_mfma_f32_16x16x32_bf16(bk, aq[kk], s[j], 0, 0, 0);
      }
    __builtin_amdgcn_s_setprio(0);

    // --- scale + causal mask (diagonal tile only) ---
    if (kt == qt) {
      const int qr = (w << 4) + lr;
#pragma unroll
      for (int j = 0; j < 4; ++j)
#pragma unroll
        for (int rg = 0; rg < 4; ++rg) {
          const int kvr = (j << 4) + (hi << 2) + rg;
          s[j][rg] = (kvr > qr) ? -1e30f : s[j][rg] * 0.125f;
        }
    } else {
#pragma unroll
      for (int j = 0; j < 4; ++j) s[j] = s[j] * 0.125f;
    }

    // --- online softmax, q = lr lane-local; reduce across hi via shfl ---
    float mx = -1e30f;
#pragma unroll
    for (int j = 0; j < 4; ++j)
#pragma unroll
      for (int rg = 0; rg < 4; ++rg) mx = fmaxf(mx, s[j][rg]);
    mx = fmaxf(mx, __shfl_xor(mx, 16));
    mx = fmaxf(mx, __shfl_xor(mx, 32));
    const float mn = fmaxf(mrun, mx);
    const float sc = __expf(mrun - mn);
    mrun = mn;
    float rs = 0.f;
#pragma unroll
    for (int j = 0; j < 4; ++j)
#pragma unroll
      for (int rg = 0; rg < 4; ++rg) {
        const float e = __expf(s[j][rg] - mn);
        s[j][rg] = e;
        rs += e;
      }
    rs += __shfl_xor(rs, 16);
    rs += __shfl_xor(rs, 32);
    lsum = lsum * sc + rs;
    float scO[4];
#pragma unroll
    for (int rg = 0; rg < 4; ++rg) scO[rg] = __shfl(sc, (hi << 2) + rg);
#pragma unroll
    for (int j2 = 0; j2 < 4; ++j2)
#pragma unroll
      for (int rg = 0; rg < 4; ++rg) ofr[j2][rg] *= scO[rg];

    // --- pack P (A-frag, pi-mapped): slot s <- s[2kk+(s>>2)][s&3] ---
    s16x8 pb[2];
#pragma unroll
    for (int kk = 0; kk < 2; ++kk)
#pragma unroll
      for (int i = 0; i < 4; ++i) {
        pb[kk][i] = (short)f2bf(s[2 * kk][i]);
        pb[kk][4 + i] = (short)f2bf(s[2 * kk + 1][i]);
      }

    // --- O += P V (V^T b64 reads, pi-mapped) ---
    __builtin_amdgcn_s_setprio(1);
#pragma unroll
    for (int kk = 0; kk < 2; ++kk)
#pragma unroll
      for (int j2 = 0; j2 < 4; ++j2) {
        const int drow = (j2 << 4) + lr;
        const int swz = (drow & 7) << 3;
        const int base = drow << 6;
        const s16x4 lo = *(const s16x4*)&Vt[cur][base + (((kk << 5) + (hi << 2)) ^ swz)];
        const s16x4 hv = *(const s16x4*)&Vt[cur][base + (((kk << 5) + 16 + (hi << 2)) ^ swz)];
        const s16x8 vb = __builtin_shufflevector(lo, hv, 0, 1, 2, 3, 4, 5, 6, 7);
        ofr[j2] = __builtin_amdgcn_mfma_f32_16x16x32_bf16(pb[kk], vb, ofr[j2], 0, 0, 0);
      }
    __builtin_amdgcn_s_setprio(0);

    if (kt < qt) {
      asm volatile("s_waitcnt vmcnt(0)" ::: "memory");
      WRITEV(cur ^ 1)
    }
    asm volatile("s_waitcnt lgkmcnt(0)" ::: "memory");
    __builtin_amdgcn_sched_barrier(0);
    __builtin_amdgcn_s_barrier();
    cur ^= 1;
  }

  // --- epilogue: lane holds O[q = hi*4+rg][d = j2*16+lr] ---
  const float rinv = 1.f / lsum;
  float rO[4];
#pragma unroll
  for (int rg = 0; rg < 4; ++rg) rO[rg] = __shfl(rinv, (hi << 2) + rg);
#pragma unroll
  for (int j2 = 0; j2 < 4; ++j2)
#pragma unroll
    for (int rg = 0; rg < 4; ++rg) {
      const int row = (qt << 6) + (w << 4) + (hi << 2) + rg;
      const int col = (h << 6) + (j2 << 4) + lr;
      o[(bT + row) * 1024 + col] = f2bf(ofr[j2][rg] * rO[rg]);
    }
#undef STAGEK
#undef LOADV
#undef WRITEV
}

// ---------------------------------------------------------------------------
extern "C" void kernel_launch(void* const* d_in, const int* in_sizes, int n_in,
                              void* d_out, int out_size, void* d_ws, size_t ws_size,
                              hipStream_t stream) {
  (void)in_sizes; (void)n_in; (void)out_size; (void)ws_size;
  const int* idx = (const int*)d_in[0];
  const float* tokE = (const float*)d_in[1];
  const float* posE = (const float*)d_in[2];
  const float* Wq = (const float*)d_in[3];
  const float* Wk = (const float*)d_in[4];
  const float* Wv = (const float*)d_in[5];
  const float* Wp = (const float*)d_in[6];
  const float* bp = (const float*)d_in[7];
  const float* ln1g = (const float*)d_in[8];
  const float* ln1b = (const float*)d_in[9];
  const float* ln2g = (const float*)d_in[10];
  const float* ln2b = (const float*)d_in[11];
  const float* W1 = (const float*)d_in[12];
  const float* b1 = (const float*)d_in[13];
  const float* W2 = (const float*)d_in[14];
  const float* b2 = (const float*)d_in[15];
  const float* lnfg = (const float*)d_in[16];
  const float* lnfb = (const float*)d_in[17];
  const float* Wlm = (const float*)d_in[18];
  const float* blm = (const float*)d_in[19];

  char* p = (char*)d_ws;
  float* x = (float*)p;   p += (size_t)BT_ * D_ * 4;
  u16* xn = (u16*)p;      p += (size_t)BT_ * D_ * 2;
  u16* qkv = (u16*)p;     p += (size_t)BT_ * 3072 * 2;
  u16* ob = (u16*)p;      p += (size_t)BT_ * D_ * 2;
  u16* hb = (u16*)p;      p += (size_t)BT_ * FF_ * 2;
  u16* WqkvT = (u16*)p;   p += (size_t)L_ * 3072 * D_ * 2;
  u16* WpT = (u16*)p;     p += (size_t)L_ * D_ * D_ * 2;
  u16* W1T = (u16*)p;     p += (size_t)L_ * FF_ * D_ * 2;
  u16* W2T = (u16*)p;     p += (size_t)L_ * D_ * FF_ * 2;
  u16* WlmT = (u16*)p;    p += (size_t)V_ * D_ * 2;

  dim3 blk(256);
  dim3 blk512(512);
  // weight convert+transpose (bf16, [N][K]) — fused, 4 launches total
  tconv_qkvp<<<dim3(32, 32, 32), blk, 0, stream>>>(Wq, Wk, Wv, Wp, WqkvT, WpT);
  tconv_w1<<<dim3(128, 32, 8), blk, 0, stream>>>(W1, W1T);
  tconv_w2<<<dim3(32, 128, 8), blk, 0, stream>>>(W2, W2T);
  tconv_kernel<<<dim3(1000, 32), blk, 0, stream>>>(Wlm, WlmT, D_, V_);

  embed_kernel<<<dim3(BT_), blk, 0, stream>>>(idx, tokE, posE, x);

  for (int l = 0; l < L_; ++l) {
    ln_kernel<<<dim3(BT_ / 4), blk, 0, stream>>>(x, ln1g + l * D_, ln1b + l * D_, xn);
    gemm_bt<0><<<dim3(24, 32), blk, 0, stream>>>(xn, WqkvT + (size_t)l * 3072 * D_,
                                                 nullptr, nullptr, qkv, BT_, 3072, D_);
    fattn_kernel<<<dim3(T_ / 64, H_, B_), blk, 0, stream>>>(qkv, ob);
    gemm_bt<1><<<dim3(8, 32), blk, 0, stream>>>(ob, WpT + (size_t)l * D_ * D_,
                                                bp + l * D_, x, nullptr, BT_, D_, D_);
    ln_kernel<<<dim3(BT_ / 4), blk, 0, stream>>>(x, ln2g + l * D_, ln2b + l * D_, xn);
    gemm256<2><<<dim3(256), blk512, 0, stream>>>(xn, W1T + (size_t)l * FF_ * D_,
                                                 b1 + l * FF_, nullptr, hb, BT_, FF_, D_, 16);
    gemm_bt<1><<<dim3(8, 32), blk, 0, stream>>>(hb, W2T + (size_t)l * D_ * FF_,
                                                b2 + l * D_, x, nullptr, BT_, D_, FF_);
  }
  ln_kernel<<<dim3(BT_ / 4), blk, 0, stream>>>(x, lnfg, lnfb, xn);
  gemm256<3><<<dim3(2000), blk512, 0, stream>>>(xn, WlmT, blm, (float*)d_out, nullptr,
                                                BT_, V_, D_, 16);
}